// Round 1
// baseline (712.107 us; speedup 1.0000x reference)
//
#include <hip/hip_runtime.h>
#include <hip/hip_bf16.h>
#include <cstdint>
#include <cstddef>

typedef __bf16 bf16;
typedef __bf16 bf16x8 __attribute__((ext_vector_type(8)));
typedef __bf16 bf16x4v __attribute__((ext_vector_type(4)));
typedef float f32x4 __attribute__((ext_vector_type(4)));

#define MFMA16(a, b, c) __builtin_amdgcn_mfma_f32_16x16x32_bf16((a), (b), (c), 0, 0, 0)

// Problem constants
constexpr int BB = 4, SS = 2048, DD = 1024, HH = 16;
constexpr int NROWS = BB * SS;                 // 8192
constexpr size_t NB = (size_t)NROWS * DD;      // elems per [B,S,D] tensor (8,388,608)
constexpr size_t NW = (size_t)DD * DD;         // elems per weight (1,048,576)

// ---------------------------------------------------------------------------
// Kernel 0a: convert 6 input tensors f32 -> bf16
// ---------------------------------------------------------------------------
struct Ptrs6 { const float* p[6]; };

__global__ __launch_bounds__(256) void cvt_in_kernel(Ptrs6 src, bf16* dst) {
    const int z = blockIdx.y;
    const size_t idx = (size_t)blockIdx.x * 256 + threadIdx.x;   // float4 index
    float4 v = ((const float4*)src.p[z])[idx];
    bf16x4v o;
    o[0] = (bf16)v.x; o[1] = (bf16)v.y; o[2] = (bf16)v.z; o[3] = (bf16)v.w;
    *(bf16x4v*)(dst + z * NB + idx * 4) = o;
}

// ---------------------------------------------------------------------------
// Kernel 0b: convert + transpose 7 weights: W[k][n] f32 -> WT[n][k] bf16
// ---------------------------------------------------------------------------
struct Ptrs7 { const float* p[7]; };

__global__ __launch_bounds__(256) void cvt_w_kernel(Ptrs7 src, bf16* dst) {
    const int z = blockIdx.z;
    const float* W = src.p[z];
    bf16* WT = dst + (size_t)z * NW;
    __shared__ float tile[32][33];
    const int tx = threadIdx.x, ty = threadIdx.y;     // (32, 8)
    const int kb = blockIdx.y * 32, nb = blockIdx.x * 32;
#pragma unroll
    for (int j = 0; j < 4; ++j)
        tile[ty + j * 8][tx] = W[(size_t)(kb + ty + j * 8) * DD + nb + tx];
    __syncthreads();
#pragma unroll
    for (int j = 0; j < 4; ++j)
        WT[(size_t)(nb + ty + j * 8) * DD + kb + tx] = (bf16)tile[tx][ty + j * 8];
}

// ---------------------------------------------------------------------------
// GEMM: C[128x128] per block, 4 waves (2x2 of 64x64), BK=64, swizzled LDS.
//   out[n][c] = sum_k A1[n][k] B1T[c][k]  (+ A2/B2T pair for kt >= split)
// MODE 0: write bf16 to head layout [b,h,s,64] (projection Q/K/V)
// MODE 1: write f32 tmp = acc + r1 + r2 (fc + residual)
// ---------------------------------------------------------------------------
struct GemmPtrs {
    const bf16* a1[3]; const bf16* a2[3];
    const bf16* b1[3]; const bf16* b2[3];
    bf16* outbh[3];
};

template <int MODE>
__global__ __launch_bounds__(256) void gemm_kernel(GemmPtrs P, int iters, int split,
                                                   float* outF, const float* r1, const float* r2) {
    const int z = blockIdx.z;
    const bf16* __restrict__ A1 = P.a1[z];
    const bf16* __restrict__ A2 = P.a2[z];
    const bf16* __restrict__ B1 = P.b1[z];
    const bf16* __restrict__ B2 = P.b2[z];

    const int tid = threadIdx.x;
    const int lane = tid & 63, w = tid >> 6;
    const int g = lane >> 4, i = lane & 15;
    const int m0 = blockIdx.y * 128, n0 = blockIdx.x * 128;
    const int mb = (w >> 1) * 64, nb = (w & 1) * 64;

    __shared__ __align__(16) bf16 As[128 * 64];
    __shared__ __align__(16) bf16 Bs[128 * 64];

    f32x4 acc[4][4];
#pragma unroll
    for (int a = 0; a < 4; ++a)
#pragma unroll
        for (int b = 0; b < 4; ++b) acc[a][b] = 0.0f;

    for (int kt = 0; kt < iters; ++kt) {
        const bf16* Ag; const bf16* Bg; int koff;
        if (kt < split) { Ag = A1; Bg = B1; koff = kt * 64; }
        else            { Ag = A2; Bg = B2; koff = (kt - split) * 64; }

        __syncthreads();
#pragma unroll
        for (int c = 0; c < 4; ++c) {
            int ci = c * 256 + tid;           // 0..1023 chunks of 16B
            int row = ci >> 3, seg = ci & 7;
            int lb = (row * 128 + seg * 16) ^ ((row & 7) << 4);
            bf16x8 va = *(const bf16x8*)(Ag + (size_t)(m0 + row) * DD + koff + seg * 8);
            bf16x8 vb = *(const bf16x8*)(Bg + (size_t)(n0 + row) * DD + koff + seg * 8);
            *(bf16x8*)((char*)As + lb) = va;
            *(bf16x8*)((char*)Bs + lb) = vb;
        }
        __syncthreads();

#pragma unroll
        for (int f = 0; f < 2; ++f) {
            bf16x8 af[4], bff[4];
#pragma unroll
            for (int mt = 0; mt < 4; ++mt) {
                int row = mb + mt * 16 + i;
                af[mt] = *(const bf16x8*)((char*)As + ((row * 128 + f * 64 + g * 16) ^ ((row & 7) << 4)));
            }
#pragma unroll
            for (int nt = 0; nt < 4; ++nt) {
                int row = nb + nt * 16 + i;
                bff[nt] = *(const bf16x8*)((char*)Bs + ((row * 128 + f * 64 + g * 16) ^ ((row & 7) << 4)));
            }
#pragma unroll
            for (int mt = 0; mt < 4; ++mt)
#pragma unroll
                for (int nt = 0; nt < 4; ++nt)
                    acc[mt][nt] = MFMA16(af[mt], bff[nt], acc[mt][nt]);
        }
    }

    if (MODE == 0) {
        bf16* outQ = P.outbh[z];
#pragma unroll
        for (int mt = 0; mt < 4; ++mt)
#pragma unroll
            for (int nt = 0; nt < 4; ++nt) {
                int colg = n0 + nb + nt * 16 + i;
                int h = colg >> 6, d = colg & 63;
#pragma unroll
                for (int r = 0; r < 4; ++r) {
                    int rowg = m0 + mb + mt * 16 + g * 4 + r;
                    int b = rowg >> 11, s = rowg & 2047;
                    outQ[(((size_t)(b * HH + h)) * SS + s) * 64 + d] = (bf16)acc[mt][nt][r];
                }
            }
    } else {
#pragma unroll
        for (int mt = 0; mt < 4; ++mt)
#pragma unroll
            for (int nt = 0; nt < 4; ++nt) {
                int colg = n0 + nb + nt * 16 + i;
#pragma unroll
                for (int r = 0; r < 4; ++r) {
                    int rowg = m0 + mb + mt * 16 + g * 4 + r;
                    size_t off = (size_t)rowg * DD + colg;
                    outF[off] = acc[mt][nt][r] + r1[off] + r2[off];
                }
            }
    }
}

// ---------------------------------------------------------------------------
// Flash attention. Grid: (32 q-tiles, 64 bh). Block 256 = 4 waves.
// Each wave owns 16 query rows; K-tile = 64 keys staged in swizzled LDS;
// V staged transposed (VT[d][k]); online softmax in registers.
// Q/K/V layout: [bh][2048][64] bf16. ctx out: [b*2048+s][h*64+d] bf16.
// ---------------------------------------------------------------------------
__global__ __launch_bounds__(256) void attn_kernel(const bf16* __restrict__ Qg,
                                                   const bf16* __restrict__ Kg,
                                                   const bf16* __restrict__ Vg,
                                                   bf16* __restrict__ ctx) {
    const int tid = threadIdx.x;
    const int lane = tid & 63, w = tid >> 6;
    const int g = lane >> 4, i = lane & 15;
    const int qt = blockIdx.x, bh = blockIdx.y;
    const size_t headoff = (size_t)bh * SS * 64;
    const int q0 = qt * 64;

    __shared__ __align__(16) bf16 Ks[64 * 64];
    __shared__ __align__(16) bf16 VTs[64 * 64];
    __shared__ __align__(16) bf16 Ps[4][16 * 64];

    // Q fragments, pre-scaled by 1/TEMP = 1/16 (exact in bf16)
    bf16x8 qa[2];
#pragma unroll
    for (int f = 0; f < 2; ++f) {
        bf16x8 v = *(const bf16x8*)(Qg + headoff + (size_t)(q0 + w * 16 + i) * 64 + f * 32 + g * 8);
#pragma unroll
        for (int e = 0; e < 8; ++e) v[e] = (bf16)((float)v[e] * 0.0625f);
        qa[f] = v;
    }

    f32x4 o[4];
#pragma unroll
    for (int nt = 0; nt < 4; ++nt) o[nt] = 0.0f;
    float m_[4], l_[4];
#pragma unroll
    for (int r = 0; r < 4; ++r) { m_[r] = -3e38f; l_[r] = 0.0f; }

    for (int kt = 0; kt < SS / 64; ++kt) {
        const int k0 = kt * 64;
        __syncthreads();
        // ---- stage K tile (swizzled rows) + V tile transposed ----
        {
            const int key = tid >> 2;
            const int s2 = (tid & 3) * 2;
            const bf16* kp = Kg + headoff + (size_t)(k0 + key) * 64;
#pragma unroll
            for (int c = 0; c < 2; ++c) {
                int seg = s2 + c;
                bf16x8 v = *(const bf16x8*)(kp + seg * 8);
                *(bf16x8*)((char*)Ks + ((key * 128 + seg * 16) ^ ((key & 7) << 4))) = v;
            }
            const int d0 = (tid & 3) * 16;
            const bf16* vp = Vg + headoff + (size_t)(k0 + key) * 64 + d0;
            bf16x8 v0 = *(const bf16x8*)vp;
            bf16x8 v1 = *(const bf16x8*)(vp + 8);
#pragma unroll
            for (int j = 0; j < 8; ++j) {
                int d = d0 + j;
                *(bf16*)((char*)VTs + ((d * 128 + key * 2) ^ ((d & 7) << 4))) = v0[j];
                d = d0 + 8 + j;
                *(bf16*)((char*)VTs + ((d * 128 + key * 2) ^ ((d & 7) << 4))) = v1[j];
            }
        }
        __syncthreads();

        // ---- S = (Q/T) K^T : per wave 16 q x 64 keys ----
        f32x4 s4[4];
#pragma unroll
        for (int nt = 0; nt < 4; ++nt) s4[nt] = 0.0f;
#pragma unroll
        for (int nt = 0; nt < 4; ++nt) {
            int krow = nt * 16 + i;
#pragma unroll
            for (int f = 0; f < 2; ++f) {
                bf16x8 kb = *(const bf16x8*)((char*)Ks + ((krow * 128 + f * 64 + g * 16) ^ ((krow & 7) << 4)));
                s4[nt] = MFMA16(qa[f], kb, s4[nt]);
            }
        }

        // ---- online softmax (rows live at (g*4+r), cols over i & nt) ----
        float pf[4][4];
#pragma unroll
        for (int r = 0; r < 4; ++r) {
            float t0 = fmaxf(fmaxf(s4[0][r], s4[1][r]), fmaxf(s4[2][r], s4[3][r]));
#pragma unroll
            for (int mask = 1; mask <= 8; mask <<= 1) t0 = fmaxf(t0, __shfl_xor(t0, mask, 64));
            float nm = fmaxf(m_[r], t0);
            float al = __expf(m_[r] - nm);
            float ps = 0.0f;
#pragma unroll
            for (int nt = 0; nt < 4; ++nt) {
                float p = __expf(s4[nt][r] - nm);
                pf[nt][r] = p; ps += p;
            }
#pragma unroll
            for (int mask = 1; mask <= 8; mask <<= 1) ps += __shfl_xor(ps, mask, 64);
            l_[r] = l_[r] * al + ps;
            m_[r] = nm;
#pragma unroll
            for (int nt = 0; nt < 4; ++nt) o[nt][r] *= al;
        }

        // ---- P -> per-wave LDS (swizzled), read back as A-fragments ----
        char* pbase = (char*)(&Ps[w][0]);
#pragma unroll
        for (int nt = 0; nt < 4; ++nt)
#pragma unroll
            for (int r = 0; r < 4; ++r) {
                int row = g * 4 + r;
                int key = nt * 16 + i;
                *(bf16*)(pbase + ((row * 128 + key * 2) ^ ((row & 7) << 4))) = (bf16)pf[nt][r];
            }
        asm volatile("s_waitcnt lgkmcnt(0)" ::: "memory");
        bf16x8 pa[2];
#pragma unroll
        for (int f = 0; f < 2; ++f)
            pa[f] = *(const bf16x8*)(pbase + ((i * 128 + f * 64 + g * 16) ^ ((i & 7) << 4)));

        // ---- O += P V ----
#pragma unroll
        for (int nt = 0; nt < 4; ++nt) {
            int drow = nt * 16 + i;
#pragma unroll
            for (int f = 0; f < 2; ++f) {
                bf16x8 vb = *(const bf16x8*)((char*)VTs + ((drow * 128 + f * 64 + g * 16) ^ ((drow & 7) << 4)));
                o[nt] = MFMA16(pa[f], vb, o[nt]);
            }
        }
    }

    // ---- write ctx ----
    const int b = bh >> 4, h = bh & 15;
#pragma unroll
    for (int r = 0; r < 4; ++r) {
        float rcp = 1.0f / l_[r];
        int qrow = q0 + w * 16 + g * 4 + r;
#pragma unroll
        for (int nt = 0; nt < 4; ++nt) {
            size_t off = ((size_t)(b * SS + qrow)) * DD + h * 64 + nt * 16 + i;
            ctx[off] = (bf16)(o[nt][r] * rcp);
        }
    }
}

// ---------------------------------------------------------------------------
// LayerNorm: one row (1024) per block of 256 threads.
// ---------------------------------------------------------------------------
__global__ __launch_bounds__(256) void ln_kernel(const float* __restrict__ tmp,
                                                 const float* __restrict__ gamma,
                                                 const float* __restrict__ beta,
                                                 float* __restrict__ out) {
    const int row = blockIdx.x;
    const int t = threadIdx.x;
    float4 v = ((const float4*)(tmp + (size_t)row * DD))[t];
    float s = v.x + v.y + v.z + v.w;
    float ss = v.x * v.x + v.y * v.y + v.z * v.z + v.w * v.w;
#pragma unroll
    for (int mask = 1; mask <= 32; mask <<= 1) {
        s += __shfl_xor(s, mask, 64);
        ss += __shfl_xor(ss, mask, 64);
    }
    __shared__ float red[8];
    const int w = t >> 6, lane = t & 63;
    if (lane == 0) { red[w] = s; red[4 + w] = ss; }
    __syncthreads();
    s = red[0] + red[1] + red[2] + red[3];
    ss = red[4] + red[5] + red[6] + red[7];
    const float mu = s * (1.0f / 1024.0f);
    const float var = ss * (1.0f / 1024.0f) - mu * mu;
    const float rs = rsqrtf(var + 1e-6f);
    float4 gm = ((const float4*)gamma)[t];
    float4 bt = ((const float4*)beta)[t];
    float4 ov;
    ov.x = (v.x - mu) * rs * gm.x + bt.x;
    ov.y = (v.y - mu) * rs * gm.y + bt.y;
    ov.z = (v.z - mu) * rs * gm.z + bt.z;
    ov.w = (v.w - mu) * rs * gm.w + bt.w;
    ((float4*)(out + (size_t)row * DD))[t] = ov;
}

// ---------------------------------------------------------------------------
// Launcher
// ---------------------------------------------------------------------------
extern "C" void kernel_launch(void* const* d_in, const int* in_sizes, int n_in,
                              void* d_out, int out_size, void* d_ws, size_t ws_size,
                              hipStream_t stream) {
    (void)in_sizes; (void)n_in; (void)out_size; (void)ws_size;

    char* ws = (char*)d_ws;
    // workspace layout (bytes):
    //   [0)              6 x bf16 input copies (16,777,216 each)  = 100,663,296
    //   [100,663,296)    7 x bf16 W^T                             =  14,680,064
    //   [115,343,360)    Q  bf16 [64][2048][64]                   =  16,777,216
    //   [132,120,576)    K  bf16                                  =  16,777,216
    //   [148,897,792)    V  bf16                                  =  16,777,216
    //   ctx bf16 aliases offset 0         (input copies dead after proj)
    //   tmp f32  aliases offset 16,777,216 (33,554,432 bytes)
    bf16* xb = (bf16*)ws;
    bf16* wT = (bf16*)(ws + 100663296ull);
    bf16* Qg = (bf16*)(ws + 115343360ull);
    bf16* Kg = (bf16*)(ws + 132120576ull);
    bf16* Vg = (bf16*)(ws + 148897792ull);
    bf16* ctx = (bf16*)ws;
    float* tmp = (float*)(ws + 16777216ull);

    {
        Ptrs6 p;
        for (int j = 0; j < 6; ++j) p.p[j] = (const float*)d_in[j];
        cvt_in_kernel<<<dim3(8192, 6), 256, 0, stream>>>(p, xb);
    }
    {
        Ptrs7 p;
        for (int j = 0; j < 7; ++j) p.p[j] = (const float*)d_in[6 + j];
        cvt_w_kernel<<<dim3(32, 32, 7), dim3(32, 8), 0, stream>>>(p, wT);
    }
    {
        GemmPtrs gp;
        gp.a1[0] = xb;           gp.a1[1] = xb + NB;     gp.a1[2] = xb + 2 * NB;
        gp.a2[0] = xb + 3 * NB;  gp.a2[1] = xb + 4 * NB; gp.a2[2] = xb + 5 * NB;
        gp.b1[0] = wT;           gp.b1[1] = wT + NW;     gp.b1[2] = wT + 2 * NW;
        gp.b2[0] = wT + 3 * NW;  gp.b2[1] = wT + 4 * NW; gp.b2[2] = wT + 5 * NW;
        gp.outbh[0] = Qg; gp.outbh[1] = Kg; gp.outbh[2] = Vg;
        gemm_kernel<0><<<dim3(8, 64, 3), 256, 0, stream>>>(gp, 32, 16, nullptr, nullptr, nullptr);
    }
    attn_kernel<<<dim3(32, 64), 256, 0, stream>>>(Qg, Kg, Vg, ctx);
    {
        GemmPtrs gp;
        for (int j = 0; j < 3; ++j) {
            gp.a1[j] = ctx; gp.a2[j] = ctx;
            gp.b1[j] = wT + 6 * NW; gp.b2[j] = wT + 6 * NW;
            gp.outbh[j] = nullptr;
        }
        gemm_kernel<1><<<dim3(8, 64, 1), 256, 0, stream>>>(gp, 16, 16, tmp,
                                                           (const float*)d_in[0],
                                                           (const float*)d_in[3]);
    }
    ln_kernel<<<dim3(8192), 256, 0, stream>>>(tmp, (const float*)d_in[13],
                                              (const float*)d_in[14], (float*)d_out);
}

// Round 2
// 552.111 us; speedup vs baseline: 1.2898x; 1.2898x over previous
//
#include <hip/hip_runtime.h>
#include <hip/hip_bf16.h>
#include <cstdint>
#include <cstddef>

typedef __bf16 bf16;
typedef __bf16 bf16x8 __attribute__((ext_vector_type(8)));
typedef __bf16 bf16x4v __attribute__((ext_vector_type(4)));
typedef __bf16 bf16x2v __attribute__((ext_vector_type(2)));
typedef float f32x4 __attribute__((ext_vector_type(4)));
typedef float f32x16 __attribute__((ext_vector_type(16)));
typedef unsigned uint2v __attribute__((ext_vector_type(2)));
typedef unsigned uint4v __attribute__((ext_vector_type(4)));

#define MFMA16(a, b, c) __builtin_amdgcn_mfma_f32_16x16x32_bf16((a), (b), (c), 0, 0, 0)
#define MFMA32(a, b, c) __builtin_amdgcn_mfma_f32_32x32x16_bf16((a), (b), (c), 0, 0, 0)
#define SWZ(row, byte) ((((row) * 128) + (byte)) ^ (((row) & 7) << 4))

// Problem constants
constexpr int BB = 4, SS = 2048, DD = 1024, HH = 16;
constexpr int NROWS = BB * SS;                 // 8192
constexpr size_t NB = (size_t)NROWS * DD;      // elems per [B,S,D] tensor
constexpr size_t NW = (size_t)DD * DD;         // elems per weight

static __device__ __forceinline__ unsigned pk2(float a, float b) {
    bf16x2v h;
    h[0] = (bf16)a; h[1] = (bf16)b;
    return __builtin_bit_cast(unsigned, h);
}

static __device__ __forceinline__ bf16x8 frag4(unsigned w0, unsigned w1, unsigned w2, unsigned w3) {
    uint4v u;
    u[0] = w0; u[1] = w1; u[2] = w2; u[3] = w3;
    return __builtin_bit_cast(bf16x8, u);
}

// ---------------------------------------------------------------------------
// Kernel 0a: convert 6 input tensors f32 -> bf16
// ---------------------------------------------------------------------------
struct Ptrs6 { const float* p[6]; };

__global__ __launch_bounds__(256) void cvt_in_kernel(Ptrs6 src, bf16* dst) {
    const int z = blockIdx.y;
    const size_t idx = (size_t)blockIdx.x * 256 + threadIdx.x;   // float4 index
    float4 v = ((const float4*)src.p[z])[idx];
    bf16x4v o;
    o[0] = (bf16)v.x; o[1] = (bf16)v.y; o[2] = (bf16)v.z; o[3] = (bf16)v.w;
    *(bf16x4v*)(dst + z * NB + idx * 4) = o;
}

// ---------------------------------------------------------------------------
// Kernel 0b: convert + transpose 7 weights: W[k][n] f32 -> WT[n][k] bf16
// ---------------------------------------------------------------------------
struct Ptrs7 { const float* p[7]; };

__global__ __launch_bounds__(256) void cvt_w_kernel(Ptrs7 src, bf16* dst) {
    const int z = blockIdx.z;
    const float* W = src.p[z];
    bf16* WT = dst + (size_t)z * NW;
    __shared__ float tile[32][33];
    const int tx = threadIdx.x, ty = threadIdx.y;     // (32, 8)
    const int kb = blockIdx.y * 32, nb = blockIdx.x * 32;
#pragma unroll
    for (int j = 0; j < 4; ++j)
        tile[ty + j * 8][tx] = W[(size_t)(kb + ty + j * 8) * DD + nb + tx];
    __syncthreads();
#pragma unroll
    for (int j = 0; j < 4; ++j)
        WT[(size_t)(nb + ty + j * 8) * DD + kb + tx] = (bf16)tile[tx][ty + j * 8];
}

// ---------------------------------------------------------------------------
// Kernel 0c: transpose V [bh][s][64] -> Vt [bh][64][2048]
// ---------------------------------------------------------------------------
__global__ __launch_bounds__(256) void vt_kernel(const bf16* __restrict__ V,
                                                 bf16* __restrict__ Vt) {
    const int bh = blockIdx.y;
    const int s0 = blockIdx.x * 64;
    __shared__ bf16 t[64][72];
    const int tid = threadIdx.x;
    const int row = tid >> 2, seg = tid & 3;          // 64 rows x 4 chunks of 16
    const bf16* src = V + ((size_t)bh * SS + s0 + row) * 64 + seg * 16;
    bf16x8 v0 = *(const bf16x8*)src;
    bf16x8 v1 = *(const bf16x8*)(src + 8);
#pragma unroll
    for (int j = 0; j < 8; ++j) {
        t[seg * 16 + j][row] = v0[j];
        t[seg * 16 + 8 + j][row] = v1[j];
    }
    __syncthreads();
    const int d = tid >> 2, c = (tid & 3) * 16;
    bf16x8 o0 = *(const bf16x8*)(&t[d][c]);
    bf16x8 o1 = *(const bf16x8*)(&t[d][c + 8]);
    bf16* dst = Vt + ((size_t)bh * 64 + d) * SS + s0 + c;
    *(bf16x8*)dst = o0;
    *(bf16x8*)(dst + 8) = o1;
}

// ---------------------------------------------------------------------------
// GEMM: C[128x128] per block, 4 waves (2x2 of 64x64), BK=64, swizzled LDS.
// MODE 0: A = row-major [8192][1024]; write bf16 to head layout [bh][s][64]
// MODE 1: A = head-major ctxh [bh][s][64]; write f32 tmp = acc + r1 + r2
// ---------------------------------------------------------------------------
struct GemmPtrs {
    const bf16* a1[3]; const bf16* a2[3];
    const bf16* b1[3]; const bf16* b2[3];
    bf16* outbh[3];
};

template <int MODE>
__global__ __launch_bounds__(256) void gemm_kernel(GemmPtrs P, int iters, int split,
                                                   float* outF, const float* r1, const float* r2) {
    const int z = blockIdx.z;
    const bf16* __restrict__ A1 = P.a1[z];
    const bf16* __restrict__ A2 = P.a2[z];
    const bf16* __restrict__ B1 = P.b1[z];
    const bf16* __restrict__ B2 = P.b2[z];

    const int tid = threadIdx.x;
    const int lane = tid & 63, w = tid >> 6;
    const int g = lane >> 4, i = lane & 15;
    const int m0 = blockIdx.y * 128, n0 = blockIdx.x * 128;
    const int mb = (w >> 1) * 64, nb = (w & 1) * 64;

    __shared__ __align__(16) bf16 As[128 * 64];
    __shared__ __align__(16) bf16 Bs[128 * 64];

    f32x4 acc[4][4];
#pragma unroll
    for (int a = 0; a < 4; ++a)
#pragma unroll
        for (int b = 0; b < 4; ++b) acc[a][b] = 0.0f;

    for (int kt = 0; kt < iters; ++kt) {
        const bf16* Ag; const bf16* Bg; int koff;
        if (kt < split) { Ag = A1; Bg = B1; koff = kt * 64; }
        else            { Ag = A2; Bg = B2; koff = (kt - split) * 64; }

        __syncthreads();
#pragma unroll
        for (int c = 0; c < 4; ++c) {
            int ci = c * 256 + tid;           // 0..1023 chunks of 16B
            int row = ci >> 3, seg = ci & 7;
            int lb = (row * 128 + seg * 16) ^ ((row & 7) << 4);
            const bf16* ap;
            if (MODE == 0) {
                ap = Ag + (size_t)(m0 + row) * DD + koff + seg * 8;
            } else {
                int gr = m0 + row;
                ap = Ag + ((size_t)((gr >> 11) * HH + (koff >> 6)) * SS + (gr & 2047)) * 64 + seg * 8;
            }
            bf16x8 va = *(const bf16x8*)ap;
            bf16x8 vb = *(const bf16x8*)(Bg + (size_t)(n0 + row) * DD + koff + seg * 8);
            *(bf16x8*)((char*)As + lb) = va;
            *(bf16x8*)((char*)Bs + lb) = vb;
        }
        __syncthreads();

#pragma unroll
        for (int f = 0; f < 2; ++f) {
            bf16x8 af[4], bff[4];
#pragma unroll
            for (int mt = 0; mt < 4; ++mt) {
                int row = mb + mt * 16 + i;
                af[mt] = *(const bf16x8*)((char*)As + ((row * 128 + f * 64 + g * 16) ^ ((row & 7) << 4)));
            }
#pragma unroll
            for (int nt = 0; nt < 4; ++nt) {
                int row = nb + nt * 16 + i;
                bff[nt] = *(const bf16x8*)((char*)Bs + ((row * 128 + f * 64 + g * 16) ^ ((row & 7) << 4)));
            }
#pragma unroll
            for (int mt = 0; mt < 4; ++mt)
#pragma unroll
                for (int nt = 0; nt < 4; ++nt)
                    acc[mt][nt] = MFMA16(af[mt], bff[nt], acc[mt][nt]);
        }
    }

    if (MODE == 0) {
        bf16* outQ = P.outbh[z];
#pragma unroll
        for (int mt = 0; mt < 4; ++mt)
#pragma unroll
            for (int nt = 0; nt < 4; ++nt) {
                int colg = n0 + nb + nt * 16 + i;
                int h = colg >> 6, d = colg & 63;
#pragma unroll
                for (int r = 0; r < 4; ++r) {
                    int rowg = m0 + mb + mt * 16 + g * 4 + r;
                    int b = rowg >> 11, s = rowg & 2047;
                    outQ[(((size_t)(b * HH + h)) * SS + s) * 64 + d] = (bf16)acc[mt][nt][r];
                }
            }
    } else {
#pragma unroll
        for (int mt = 0; mt < 4; ++mt)
#pragma unroll
            for (int nt = 0; nt < 4; ++nt) {
                int colg = n0 + nb + nt * 16 + i;
#pragma unroll
                for (int r = 0; r < 4; ++r) {
                    int rowg = m0 + mb + mt * 16 + g * 4 + r;
                    size_t off = (size_t)rowg * DD + colg;
                    outF[off] = acc[mt][nt][r] + r1[off] + r2[off];
                }
            }
    }
}

// ---------------------------------------------------------------------------
// Flash attention v2: 8 waves x 32 queries, KVBLK=64, swapped QK^T and PV.
// Q/K: [bh][2048][64] bf16;  Vt: [bh][64][2048] bf16;  ctxh: [bh][2048][64].
// Each lane owns one query row (q = lane&31); softmax fully in registers.
// ---------------------------------------------------------------------------
__global__ __launch_bounds__(512, 4) void attn_kernel(const bf16* __restrict__ Qg,
                                                      const bf16* __restrict__ Kg,
                                                      const bf16* __restrict__ Vt,
                                                      bf16* __restrict__ ctxh) {
    const int bid = blockIdx.x;
    // XCD-grouped: the 8 q-tiles of one bh land on the same XCD (bid mod 8 fixed)
    const int bh = ((bid & 7) << 3) | (bid >> 6);
    const int qt = (bid >> 3) & 7;

    const int tid = threadIdx.x;
    const int lane = tid & 63, w = tid >> 6;
    const int hi = lane >> 5, q = lane & 31;

    __shared__ __align__(16) char smem[32768];   // 2 x (K 8KB + Vt 8KB); reused for O tile

    // Q fragments (B-operand), prescaled by 1/TEMP = 1/16 (exact in bf16)
    const int qrow = qt * 256 + w * 32 + q;
    bf16x8 qf[4];
    {
        const bf16* qp = Qg + ((size_t)bh * SS + qrow) * 64;
#pragma unroll
        for (int c = 0; c < 4; ++c) {
            bf16x8 v = *(const bf16x8*)(qp + c * 16 + hi * 8);
#pragma unroll
            for (int e = 0; e < 8; ++e) v[e] = (bf16)((float)v[e] * 0.0625f);
            qf[c] = v;
        }
    }

    // staging: thread t loads 16B of K row (t>>3) and Vt row (t>>3)
    const int srow = tid >> 3, sseg = tid & 7;
    const bf16* kgp = Kg + (size_t)bh * SS * 64;
    const bf16* vgp = Vt + (size_t)bh * 64 * SS;
    const int sbyte = SWZ(srow, sseg * 16);

    bf16x8 kreg = *(const bf16x8*)(kgp + (size_t)srow * 64 + sseg * 8);
    bf16x8 vreg = *(const bf16x8*)(vgp + (size_t)srow * SS + sseg * 8);

    f32x16 o0 = {}, o1 = {};
    float m = -3e38f, l = 0.0f;

    for (int kt = 0; kt < SS / 64; ++kt) {
        char* kb_ = smem + (kt & 1) * 16384;
        char* vb_ = kb_ + 8192;
        *(bf16x8*)(kb_ + sbyte) = kreg;
        *(bf16x8*)(vb_ + sbyte) = vreg;
        if (kt + 1 < SS / 64) {     // issue-early loads for next tile (T14)
            const int k0n = (kt + 1) * 64;
            kreg = *(const bf16x8*)(kgp + (size_t)(k0n + srow) * 64 + sseg * 8);
            vreg = *(const bf16x8*)(vgp + (size_t)srow * SS + k0n + sseg * 8);
        }
        __syncthreads();

        // ---- S^T = K (Q/T)^T : lane holds 32 scores of ITS query row ----
        f32x16 st0 = {}, st1 = {};
#pragma unroll
        for (int c = 0; c < 4; ++c) {
            bf16x8 kf = *(const bf16x8*)(kb_ + SWZ(q, c * 32 + hi * 16));
            st0 = MFMA32(kf, qf[c], st0);
        }
#pragma unroll
        for (int c = 0; c < 4; ++c) {
            bf16x8 kf = *(const bf16x8*)(kb_ + SWZ(32 + q, c * 32 + hi * 16));
            st1 = MFMA32(kf, qf[c], st1);
        }

        // ---- online softmax, in-lane + one cross-half shuffle ----
        float tm = st0[0];
#pragma unroll
        for (int r = 1; r < 16; ++r) tm = fmaxf(tm, st0[r]);
#pragma unroll
        for (int r = 0; r < 16; ++r) tm = fmaxf(tm, st1[r]);
        tm = fmaxf(tm, __shfl_xor(tm, 32, 64));
        if (!__all(tm - m <= 8.0f)) {     // defer-max (T13)
            float nm = fmaxf(m, tm);
            float al = __expf(m - nm);
            l *= al;
            o0 *= al;
            o1 *= al;
            m = nm;
        }
        float sum = 0.0f;
#pragma unroll
        for (int r = 0; r < 16; ++r) { st0[r] = __expf(st0[r] - m); sum += st0[r]; }
#pragma unroll
        for (int r = 0; r < 16; ++r) { st1[r] = __expf(st1[r] - m); sum += st1[r]; }
        l += sum;

        // ---- pack P -> B-fragments via cvt_pk + permlane32_swap (T12) ----
        bf16x8 pf[4];
#pragma unroll
        for (int c = 0; c < 4; ++c) {
            const f32x16 s_ = (c < 2) ? st0 : st1;
            const int b0 = (c & 1) * 8;
            unsigned a0 = pk2(s_[b0 + 0], s_[b0 + 1]);
            unsigned c0 = pk2(s_[b0 + 4], s_[b0 + 5]);
            unsigned a1 = pk2(s_[b0 + 2], s_[b0 + 3]);
            unsigned c1 = pk2(s_[b0 + 6], s_[b0 + 7]);
            uint2v s1 = __builtin_amdgcn_permlane32_swap(a0, c0, false, false);
            uint2v s2 = __builtin_amdgcn_permlane32_swap(a1, c1, false, false);
            pf[c] = frag4(s1[0], s2[0], s1[1], s2[1]);
        }

        // ---- O^T += Vt P^T : output col = lane&31 = q (lane-local softmax!) ----
#pragma unroll
        for (int c = 0; c < 4; ++c) {
            bf16x8 vf = *(const bf16x8*)(vb_ + SWZ(q, c * 32 + hi * 16));
            o0 = MFMA32(vf, pf[c], o0);
        }
#pragma unroll
        for (int c = 0; c < 4; ++c) {
            bf16x8 vf = *(const bf16x8*)(vb_ + SWZ(32 + q, c * 32 + hi * 16));
            o1 = MFMA32(vf, pf[c], o1);
        }
    }

    // ---- epilogue: normalize, stage O tile in LDS, coalesced global write ----
    float lt = l + __shfl_xor(l, 32, 64);
    float rl = 1.0f / lt;
    __syncthreads();    // all waves done with staging buffers
    const int orow = w * 32 + q;
#pragma unroll
    for (int dh = 0; dh < 2; ++dh) {
#pragma unroll
        for (int r = 0; r < 16; r += 2) {
            float v0 = (dh ? o1[r] : o0[r]) * rl;
            float v1 = (dh ? o1[r + 1] : o0[r + 1]) * rl;
            int d = dh * 32 + (r & 3) + 8 * (r >> 2) + 4 * hi;
            *(unsigned*)(smem + SWZ(orow, d * 2)) = pk2(v0, v1);
        }
    }
    __syncthreads();
    {
        const int row = tid >> 1, hf = tid & 1;
        bf16* outp = ctxh + ((size_t)bh * SS + qt * 256 + row) * 64 + hf * 32;
#pragma unroll
        for (int c = 0; c < 4; ++c) {
            bf16x8 v = *(const bf16x8*)(smem + SWZ(row, hf * 64 + c * 16));
            *(bf16x8*)(outp + c * 8) = v;
        }
    }
}

// ---------------------------------------------------------------------------
// LayerNorm: one row (1024) per block of 256 threads.
// ---------------------------------------------------------------------------
__global__ __launch_bounds__(256) void ln_kernel(const float* __restrict__ tmp,
                                                 const float* __restrict__ gamma,
                                                 const float* __restrict__ beta,
                                                 float* __restrict__ out) {
    const int row = blockIdx.x;
    const int t = threadIdx.x;
    float4 v = ((const float4*)(tmp + (size_t)row * DD))[t];
    float s = v.x + v.y + v.z + v.w;
    float ss = v.x * v.x + v.y * v.y + v.z * v.z + v.w * v.w;
#pragma unroll
    for (int mask = 1; mask <= 32; mask <<= 1) {
        s += __shfl_xor(s, mask, 64);
        ss += __shfl_xor(ss, mask, 64);
    }
    __shared__ float red[8];
    const int w = t >> 6, lane = t & 63;
    if (lane == 0) { red[w] = s; red[4 + w] = ss; }
    __syncthreads();
    s = red[0] + red[1] + red[2] + red[3];
    ss = red[4] + red[5] + red[6] + red[7];
    const float mu = s * (1.0f / 1024.0f);
    const float var = ss * (1.0f / 1024.0f) - mu * mu;
    const float rs = rsqrtf(var + 1e-6f);
    float4 gm = ((const float4*)gamma)[t];
    float4 bt = ((const float4*)beta)[t];
    float4 ov;
    ov.x = (v.x - mu) * rs * gm.x + bt.x;
    ov.y = (v.y - mu) * rs * gm.y + bt.y;
    ov.z = (v.z - mu) * rs * gm.z + bt.z;
    ov.w = (v.w - mu) * rs * gm.w + bt.w;
    ((float4*)(out + (size_t)row * DD))[t] = ov;
}

// ---------------------------------------------------------------------------
// Launcher
// ---------------------------------------------------------------------------
extern "C" void kernel_launch(void* const* d_in, const int* in_sizes, int n_in,
                              void* d_out, int out_size, void* d_ws, size_t ws_size,
                              hipStream_t stream) {
    (void)in_sizes; (void)n_in; (void)out_size; (void)ws_size;

    char* ws = (char*)d_ws;
    // workspace layout (bytes):
    //   [0)              6 x bf16 input copies (16,777,216 each)  = 100,663,296
    //     after proj these are dead; aliased:
    //       ctxh bf16 [bh][2048][64]  at 0
    //       Vt   bf16 [bh][64][2048]  at 16,777,216
    //       tmp  f32  [8192][1024]    at 33,554,432
    //   [100,663,296)    7 x bf16 W^T                             =  14,680,064
    //   [115,343,360)    Q  bf16 [bh][2048][64]
    //   [132,120,576)    K  bf16
    //   [148,897,792)    V  bf16                    (end 165,675,008)
    bf16* xb = (bf16*)ws;
    bf16* wT = (bf16*)(ws + 100663296ull);
    bf16* Qg = (bf16*)(ws + 115343360ull);
    bf16* Kg = (bf16*)(ws + 132120576ull);
    bf16* Vg = (bf16*)(ws + 148897792ull);
    bf16* ctxh = (bf16*)ws;
    bf16* Vtg = (bf16*)(ws + 16777216ull);
    float* tmp = (float*)(ws + 33554432ull);

    {
        Ptrs6 p;
        for (int j = 0; j < 6; ++j) p.p[j] = (const float*)d_in[j];
        cvt_in_kernel<<<dim3(8192, 6), 256, 0, stream>>>(p, xb);
    }
    {
        Ptrs7 p;
        for (int j = 0; j < 7; ++j) p.p[j] = (const float*)d_in[6 + j];
        cvt_w_kernel<<<dim3(32, 32, 7), dim3(32, 8), 0, stream>>>(p, wT);
    }
    {
        GemmPtrs gp;
        gp.a1[0] = xb;           gp.a1[1] = xb + NB;     gp.a1[2] = xb + 2 * NB;
        gp.a2[0] = xb + 3 * NB;  gp.a2[1] = xb + 4 * NB; gp.a2[2] = xb + 5 * NB;
        gp.b1[0] = wT;           gp.b1[1] = wT + NW;     gp.b1[2] = wT + 2 * NW;
        gp.b2[0] = wT + 3 * NW;  gp.b2[1] = wT + 4 * NW; gp.b2[2] = wT + 5 * NW;
        gp.outbh[0] = Qg; gp.outbh[1] = Kg; gp.outbh[2] = Vg;
        gemm_kernel<0><<<dim3(8, 64, 3), 256, 0, stream>>>(gp, 32, 16, nullptr, nullptr, nullptr);
    }
    vt_kernel<<<dim3(32, 64), 256, 0, stream>>>(Vg, Vtg);
    attn_kernel<<<dim3(512), 512, 0, stream>>>(Qg, Kg, Vtg, ctxh);
    {
        GemmPtrs gp;
        for (int j = 0; j < 3; ++j) {
            gp.a1[j] = ctxh; gp.a2[j] = ctxh;
            gp.b1[j] = wT + 6 * NW; gp.b2[j] = wT + 6 * NW;
            gp.outbh[j] = nullptr;
        }
        gemm_kernel<1><<<dim3(8, 64, 1), 256, 0, stream>>>(gp, 16, 16, tmp,
                                                           (const float*)d_in[0],
                                                           (const float*)d_in[3]);
    }
    ln_kernel<<<dim3(8192), 256, 0, stream>>>(tmp, (const float*)d_in[13],
                                              (const float*)d_in[14], (float*)d_out);
}

// Round 3
// 533.038 us; speedup vs baseline: 1.3359x; 1.0358x over previous
//
#include <hip/hip_runtime.h>
#include <hip/hip_bf16.h>
#include <cstdint>
#include <cstddef>

typedef __bf16 bf16;
typedef __bf16 bf16x8 __attribute__((ext_vector_type(8)));
typedef __bf16 bf16x4v __attribute__((ext_vector_type(4)));
typedef __bf16 bf16x2v __attribute__((ext_vector_type(2)));
typedef float f32x4 __attribute__((ext_vector_type(4)));
typedef float f32x16 __attribute__((ext_vector_type(16)));
typedef unsigned uint2v __attribute__((ext_vector_type(2)));
typedef unsigned uint4v __attribute__((ext_vector_type(4)));

#define MFMA16(a, b, c) __builtin_amdgcn_mfma_f32_16x16x32_bf16((a), (b), (c), 0, 0, 0)
#define MFMA32(a, b, c) __builtin_amdgcn_mfma_f32_32x32x16_bf16((a), (b), (c), 0, 0, 0)
#define SWZ(row, byte) ((((row) * 128) + (byte)) ^ (((row) & 7) << 4))
#define GLOAD_LDS(g, l) \
    __builtin_amdgcn_global_load_lds((const __attribute__((address_space(1))) void*)(g), \
                                     (__attribute__((address_space(3))) void*)(l), 16, 0, 0)

// Problem constants
constexpr int BB = 4, SS = 2048, DD = 1024, HH = 16;
constexpr int NROWS = BB * SS;                 // 8192
constexpr size_t NB = (size_t)NROWS * DD;      // elems per [B,S,D] tensor
constexpr size_t NW = (size_t)DD * DD;         // elems per weight

static __device__ __forceinline__ unsigned pk2(float a, float b) {
    bf16x2v h;
    h[0] = (bf16)a; h[1] = (bf16)b;
    return __builtin_bit_cast(unsigned, h);
}

static __device__ __forceinline__ bf16x8 frag4(unsigned w0, unsigned w1, unsigned w2, unsigned w3) {
    uint4v u;
    u[0] = w0; u[1] = w1; u[2] = w2; u[3] = w3;
    return __builtin_bit_cast(bf16x8, u);
}

// ---------------------------------------------------------------------------
// Kernel 0a: convert 6 input tensors f32 -> bf16
// ---------------------------------------------------------------------------
struct Ptrs6 { const float* p[6]; };

__global__ __launch_bounds__(256) void cvt_in_kernel(Ptrs6 src, bf16* dst) {
    const int z = blockIdx.y;
    const size_t idx = (size_t)blockIdx.x * 256 + threadIdx.x;   // float4 index
    float4 v = ((const float4*)src.p[z])[idx];
    bf16x4v o;
    o[0] = (bf16)v.x; o[1] = (bf16)v.y; o[2] = (bf16)v.z; o[3] = (bf16)v.w;
    *(bf16x4v*)(dst + z * NB + idx * 4) = o;
}

// ---------------------------------------------------------------------------
// Kernel 0b: convert + transpose 7 weights: W[k][n] f32 -> WT[n][k] bf16
// ---------------------------------------------------------------------------
struct Ptrs7 { const float* p[7]; };

__global__ __launch_bounds__(256) void cvt_w_kernel(Ptrs7 src, bf16* dst) {
    const int z = blockIdx.z;
    const float* W = src.p[z];
    bf16* WT = dst + (size_t)z * NW;
    __shared__ float tile[32][33];
    const int tx = threadIdx.x, ty = threadIdx.y;     // (32, 8)
    const int kb = blockIdx.y * 32, nb = blockIdx.x * 32;
#pragma unroll
    for (int j = 0; j < 4; ++j)
        tile[ty + j * 8][tx] = W[(size_t)(kb + ty + j * 8) * DD + nb + tx];
    __syncthreads();
#pragma unroll
    for (int j = 0; j < 4; ++j)
        WT[(size_t)(nb + ty + j * 8) * DD + kb + tx] = (bf16)tile[tx][ty + j * 8];
}

// ---------------------------------------------------------------------------
// Kernel 0c: transpose V [bh][s][64] -> Vt [bh][64][2048]
// ---------------------------------------------------------------------------
__global__ __launch_bounds__(256) void vt_kernel(const bf16* __restrict__ V,
                                                 bf16* __restrict__ Vt) {
    const int bh = blockIdx.y;
    const int s0 = blockIdx.x * 64;
    __shared__ bf16 t[64][72];
    const int tid = threadIdx.x;
    const int row = tid >> 2, seg = tid & 3;          // 64 rows x 4 chunks of 16
    const bf16* src = V + ((size_t)bh * SS + s0 + row) * 64 + seg * 16;
    bf16x8 v0 = *(const bf16x8*)src;
    bf16x8 v1 = *(const bf16x8*)(src + 8);
#pragma unroll
    for (int j = 0; j < 8; ++j) {
        t[seg * 16 + j][row] = v0[j];
        t[seg * 16 + 8 + j][row] = v1[j];
    }
    __syncthreads();
    const int d = tid >> 2, c = (tid & 3) * 16;
    bf16x8 o0 = *(const bf16x8*)(&t[d][c]);
    bf16x8 o1 = *(const bf16x8*)(&t[d][c + 8]);
    bf16* dst = Vt + ((size_t)bh * 64 + d) * SS + s0 + c;
    *(bf16x8*)dst = o0;
    *(bf16x8*)(dst + 8) = o1;
}

// ---------------------------------------------------------------------------
// GEMM: C[128x128] per block, 4 waves (2x2 of 64x64), BK=64.
// Staging: global_load_lds width=16, linear LDS dest, inverse-swizzled global
// source chunk (seg ^ row&7) == read-side SWZ (rule 21 both-sides involution).
// 1D grid + bijective XCD swizzle (T1): 8 col-blocks of one A-panel share L2.
// MODE 0: A = row-major [8192][1024]; write bf16 to head layout [bh][s][64]
// MODE 1: A = head-major ctxh [bh][s][64]; write f32 tmp = acc + r1 + r2
// ---------------------------------------------------------------------------
struct GemmPtrs {
    const bf16* a1[3]; const bf16* a2[3];
    const bf16* b1[3]; const bf16* b2[3];
    bf16* outbh[3];
};

template <int MODE>
__global__ __launch_bounds__(256) void gemm_kernel(GemmPtrs P, int iters, int split,
                                                   float* outF, const float* r1, const float* r2) {
    // --- XCD swizzle: work = (bid%8)*cpx + bid/8 ; grid is multiple of 8 ---
    const int cpx = gridDim.x >> 3;
    const int bid0 = blockIdx.x;
    const int work = (bid0 & 7) * cpx + (bid0 >> 3);
    const int z = work >> 9;                  // 512 works (64y x 8x) per z
    const int rem = work & 511;
    const int m0 = (rem >> 3) * 128, n0 = (rem & 7) * 128;

    const bf16* __restrict__ A1 = P.a1[z];
    const bf16* __restrict__ A2 = P.a2[z];
    const bf16* __restrict__ B1 = P.b1[z];
    const bf16* __restrict__ B2 = P.b2[z];

    const int tid = threadIdx.x;
    const int lane = tid & 63, w = tid >> 6;
    const int g = lane >> 4, i = lane & 15;
    const int mb = (w >> 1) * 64, nb = (w & 1) * 64;

    __shared__ __align__(16) bf16 As[128 * 64];
    __shared__ __align__(16) bf16 Bs[128 * 64];

    // staging geometry: wave w, issue c covers LDS rows [(w*4+c)*8, +8)
    const int lrow = lane >> 3, lseg = lane & 7;
    const int chunk = lseg ^ lrow;            // pre-swizzled source chunk

    f32x4 acc[4][4];
#pragma unroll
    for (int aa = 0; aa < 4; ++aa)
#pragma unroll
        for (int bb = 0; bb < 4; ++bb) acc[aa][bb] = 0.0f;

    for (int kt = 0; kt < iters; ++kt) {
        const bf16* Ag; const bf16* Bg; int koff;
        if (kt < split) { Ag = A1; Bg = B1; koff = kt * 64; }
        else            { Ag = A2; Bg = B2; koff = (kt - split) * 64; }

        __syncthreads();
#pragma unroll
        for (int c = 0; c < 4; ++c) {
            const int row = (w * 4 + c) * 8 + lrow;
            const bf16* ap;
            if (MODE == 0) {
                ap = Ag + (size_t)(m0 + row) * DD + koff + chunk * 8;
            } else {
                int gr = m0 + row;
                ap = Ag + ((size_t)((gr >> 11) * HH + (koff >> 6)) * SS + (gr & 2047)) * 64 + chunk * 8;
            }
            const bf16* bp = Bg + (size_t)(n0 + row) * DD + koff + chunk * 8;
            GLOAD_LDS(ap, As + (w * 4 + c) * 512);
            GLOAD_LDS(bp, Bs + (w * 4 + c) * 512);
        }
        __syncthreads();   // drains vmcnt(0): tiles staged

#pragma unroll
        for (int f = 0; f < 2; ++f) {
            bf16x8 af[4], bff[4];
#pragma unroll
            for (int mt = 0; mt < 4; ++mt) {
                int row = mb + mt * 16 + i;
                af[mt] = *(const bf16x8*)((char*)As + SWZ(row, f * 64 + g * 16));
            }
#pragma unroll
            for (int nt = 0; nt < 4; ++nt) {
                int row = nb + nt * 16 + i;
                bff[nt] = *(const bf16x8*)((char*)Bs + SWZ(row, f * 64 + g * 16));
            }
#pragma unroll
            for (int mt = 0; mt < 4; ++mt)
#pragma unroll
                for (int nt = 0; nt < 4; ++nt)
                    acc[mt][nt] = MFMA16(af[mt], bff[nt], acc[mt][nt]);
        }
    }

    if (MODE == 0) {
        bf16* outQ = P.outbh[z];
#pragma unroll
        for (int mt = 0; mt < 4; ++mt)
#pragma unroll
            for (int nt = 0; nt < 4; ++nt) {
                int colg = n0 + nb + nt * 16 + i;
                int h = colg >> 6, d = colg & 63;
#pragma unroll
                for (int r = 0; r < 4; ++r) {
                    int rowg = m0 + mb + mt * 16 + g * 4 + r;
                    int b = rowg >> 11, s = rowg & 2047;
                    outQ[(((size_t)(b * HH + h)) * SS + s) * 64 + d] = (bf16)acc[mt][nt][r];
                }
            }
    } else {
#pragma unroll
        for (int mt = 0; mt < 4; ++mt)
#pragma unroll
            for (int nt = 0; nt < 4; ++nt) {
                int colg = n0 + nb + nt * 16 + i;
#pragma unroll
                for (int r = 0; r < 4; ++r) {
                    int rowg = m0 + mb + mt * 16 + g * 4 + r;
                    size_t off = (size_t)rowg * DD + colg;
                    outF[off] = acc[mt][nt][r] + r1[off] + r2[off];
                }
            }
    }
}

// ---------------------------------------------------------------------------
// Flash attention v2: 8 waves x 32 queries, KVBLK=64, swapped QK^T and PV.
// Q/K: [bh][2048][64] bf16;  Vt: [bh][64][2048] bf16;  ctxh: [bh][2048][64].
// Each lane owns one query row (q = lane&31); softmax fully in registers.
// ---------------------------------------------------------------------------
__global__ __launch_bounds__(512, 4) void attn_kernel(const bf16* __restrict__ Qg,
                                                      const bf16* __restrict__ Kg,
                                                      const bf16* __restrict__ Vt,
                                                      bf16* __restrict__ ctxh) {
    const int bid = blockIdx.x;
    // XCD-grouped: the 8 q-tiles of one bh land on the same XCD (bid mod 8 fixed)
    const int bh = ((bid & 7) << 3) | (bid >> 6);
    const int qt = (bid >> 3) & 7;

    const int tid = threadIdx.x;
    const int lane = tid & 63, w = tid >> 6;
    const int hi = lane >> 5, q = lane & 31;

    __shared__ __align__(16) char smem[32768];   // 2 x (K 8KB + Vt 8KB); reused for O tile

    // Q fragments (B-operand), prescaled by 1/TEMP = 1/16 (exact in bf16)
    const int qrow = qt * 256 + w * 32 + q;
    bf16x8 qf[4];
    {
        const bf16* qp = Qg + ((size_t)bh * SS + qrow) * 64;
#pragma unroll
        for (int c = 0; c < 4; ++c) {
            bf16x8 v = *(const bf16x8*)(qp + c * 16 + hi * 8);
#pragma unroll
            for (int e = 0; e < 8; ++e) v[e] = (bf16)((float)v[e] * 0.0625f);
            qf[c] = v;
        }
    }

    // staging: thread t loads 16B of K row (t>>3) and Vt row (t>>3)
    const int srow = tid >> 3, sseg = tid & 7;
    const bf16* kgp = Kg + (size_t)bh * SS * 64;
    const bf16* vgp = Vt + (size_t)bh * 64 * SS;
    const int sbyte = SWZ(srow, sseg * 16);

    bf16x8 kreg = *(const bf16x8*)(kgp + (size_t)srow * 64 + sseg * 8);
    bf16x8 vreg = *(const bf16x8*)(vgp + (size_t)srow * SS + sseg * 8);

    f32x16 o0 = {}, o1 = {};
    float m = -3e38f, l = 0.0f;

    for (int kt = 0; kt < SS / 64; ++kt) {
        char* kb_ = smem + (kt & 1) * 16384;
        char* vb_ = kb_ + 8192;
        *(bf16x8*)(kb_ + sbyte) = kreg;
        *(bf16x8*)(vb_ + sbyte) = vreg;
        if (kt + 1 < SS / 64) {     // issue-early loads for next tile (T14)
            const int k0n = (kt + 1) * 64;
            kreg = *(const bf16x8*)(kgp + (size_t)(k0n + srow) * 64 + sseg * 8);
            vreg = *(const bf16x8*)(vgp + (size_t)srow * SS + k0n + sseg * 8);
        }
        __syncthreads();

        // ---- S^T = K (Q/T)^T : lane holds 32 scores of ITS query row ----
        f32x16 st0 = {}, st1 = {};
        __builtin_amdgcn_s_setprio(1);
#pragma unroll
        for (int c = 0; c < 4; ++c) {
            bf16x8 kf = *(const bf16x8*)(kb_ + SWZ(q, c * 32 + hi * 16));
            st0 = MFMA32(kf, qf[c], st0);
        }
#pragma unroll
        for (int c = 0; c < 4; ++c) {
            bf16x8 kf = *(const bf16x8*)(kb_ + SWZ(32 + q, c * 32 + hi * 16));
            st1 = MFMA32(kf, qf[c], st1);
        }
        __builtin_amdgcn_s_setprio(0);

        // ---- online softmax, in-lane + one cross-half shuffle ----
        float tm = st0[0];
#pragma unroll
        for (int r = 1; r < 16; ++r) tm = fmaxf(tm, st0[r]);
#pragma unroll
        for (int r = 0; r < 16; ++r) tm = fmaxf(tm, st1[r]);
        tm = fmaxf(tm, __shfl_xor(tm, 32, 64));
        if (!__all(tm - m <= 8.0f)) {     // defer-max (T13)
            float nm = fmaxf(m, tm);
            float al = __expf(m - nm);
            l *= al;
            o0 *= al;
            o1 *= al;
            m = nm;
        }
        float sum = 0.0f;
#pragma unroll
        for (int r = 0; r < 16; ++r) { st0[r] = __expf(st0[r] - m); sum += st0[r]; }
#pragma unroll
        for (int r = 0; r < 16; ++r) { st1[r] = __expf(st1[r] - m); sum += st1[r]; }
        l += sum;

        // ---- pack P -> B-fragments via cvt_pk + permlane32_swap (T12) ----
        bf16x8 pf[4];
#pragma unroll
        for (int c = 0; c < 4; ++c) {
            const f32x16 s_ = (c < 2) ? st0 : st1;
            const int b0 = (c & 1) * 8;
            unsigned a0 = pk2(s_[b0 + 0], s_[b0 + 1]);
            unsigned c0 = pk2(s_[b0 + 4], s_[b0 + 5]);
            unsigned a1 = pk2(s_[b0 + 2], s_[b0 + 3]);
            unsigned c1 = pk2(s_[b0 + 6], s_[b0 + 7]);
            uint2v s1 = __builtin_amdgcn_permlane32_swap(a0, c0, false, false);
            uint2v s2 = __builtin_amdgcn_permlane32_swap(a1, c1, false, false);
            pf[c] = frag4(s1[0], s2[0], s1[1], s2[1]);
        }

        // ---- O^T += Vt P^T : output col = lane&31 = q (lane-local softmax!) ----
        __builtin_amdgcn_s_setprio(1);
#pragma unroll
        for (int c = 0; c < 4; ++c) {
            bf16x8 vf = *(const bf16x8*)(vb_ + SWZ(q, c * 32 + hi * 16));
            o0 = MFMA32(vf, pf[c], o0);
        }
#pragma unroll
        for (int c = 0; c < 4; ++c) {
            bf16x8 vf = *(const bf16x8*)(vb_ + SWZ(32 + q, c * 32 + hi * 16));
            o1 = MFMA32(vf, pf[c], o1);
        }
        __builtin_amdgcn_s_setprio(0);
    }

    // ---- epilogue: normalize, stage O tile in LDS, coalesced global write ----
    float lt = l + __shfl_xor(l, 32, 64);
    float rl = 1.0f / lt;
    __syncthreads();    // all waves done with staging buffers
    const int orow = w * 32 + q;
#pragma unroll
    for (int dh = 0; dh < 2; ++dh) {
#pragma unroll
        for (int r = 0; r < 16; r += 2) {
            float v0 = (dh ? o1[r] : o0[r]) * rl;
            float v1 = (dh ? o1[r + 1] : o0[r + 1]) * rl;
            int d = dh * 32 + (r & 3) + 8 * (r >> 2) + 4 * hi;
            *(unsigned*)(smem + SWZ(orow, d * 2)) = pk2(v0, v1);
        }
    }
    __syncthreads();
    {
        const int row = tid >> 1, hf = tid & 1;
        bf16* outp = ctxh + ((size_t)bh * SS + qt * 256 + row) * 64 + hf * 32;
#pragma unroll
        for (int c = 0; c < 4; ++c) {
            bf16x8 v = *(const bf16x8*)(smem + SWZ(row, hf * 64 + c * 16));
            *(bf16x8*)(outp + c * 8) = v;
        }
    }
}

// ---------------------------------------------------------------------------
// LayerNorm: one row (1024) per block of 256 threads.
// ---------------------------------------------------------------------------
__global__ __launch_bounds__(256) void ln_kernel(const float* __restrict__ tmp,
                                                 const float* __restrict__ gamma,
                                                 const float* __restrict__ beta,
                                                 float* __restrict__ out) {
    const int row = blockIdx.x;
    const int t = threadIdx.x;
    float4 v = ((const float4*)(tmp + (size_t)row * DD))[t];
    float s = v.x + v.y + v.z + v.w;
    float ss = v.x * v.x + v.y * v.y + v.z * v.z + v.w * v.w;
#pragma unroll
    for (int mask = 1; mask <= 32; mask <<= 1) {
        s += __shfl_xor(s, mask, 64);
        ss += __shfl_xor(ss, mask, 64);
    }
    __shared__ float red[8];
    const int w = t >> 6, lane = t & 63;
    if (lane == 0) { red[w] = s; red[4 + w] = ss; }
    __syncthreads();
    s = red[0] + red[1] + red[2] + red[3];
    ss = red[4] + red[5] + red[6] + red[7];
    const float mu = s * (1.0f / 1024.0f);
    const float var = ss * (1.0f / 1024.0f) - mu * mu;
    const float rs = rsqrtf(var + 1e-6f);
    float4 gm = ((const float4*)gamma)[t];
    float4 bt = ((const float4*)beta)[t];
    float4 ov;
    ov.x = (v.x - mu) * rs * gm.x + bt.x;
    ov.y = (v.y - mu) * rs * gm.y + bt.y;
    ov.z = (v.z - mu) * rs * gm.z + bt.z;
    ov.w = (v.w - mu) * rs * gm.w + bt.w;
    ((float4*)(out + (size_t)row * DD))[t] = ov;
}

// ---------------------------------------------------------------------------
// Launcher
// ---------------------------------------------------------------------------
extern "C" void kernel_launch(void* const* d_in, const int* in_sizes, int n_in,
                              void* d_out, int out_size, void* d_ws, size_t ws_size,
                              hipStream_t stream) {
    (void)in_sizes; (void)n_in; (void)out_size; (void)ws_size;

    char* ws = (char*)d_ws;
    // workspace layout (bytes):
    //   [0)              6 x bf16 input copies (16,777,216 each)  = 100,663,296
    //     after proj these are dead; aliased:
    //       ctxh bf16 [bh][2048][64]  at 0
    //       Vt   bf16 [bh][64][2048]  at 16,777,216
    //       tmp  f32  [8192][1024]    at 33,554,432
    //   [100,663,296)    7 x bf16 W^T                             =  14,680,064
    //   [115,343,360)    Q  bf16 [bh][2048][64]
    //   [132,120,576)    K  bf16
    //   [148,897,792)    V  bf16                    (end 165,675,008)
    bf16* xb = (bf16*)ws;
    bf16* wT = (bf16*)(ws + 100663296ull);
    bf16* Qg = (bf16*)(ws + 115343360ull);
    bf16* Kg = (bf16*)(ws + 132120576ull);
    bf16* Vg = (bf16*)(ws + 148897792ull);
    bf16* ctxh = (bf16*)ws;
    bf16* Vtg = (bf16*)(ws + 16777216ull);
    float* tmp = (float*)(ws + 33554432ull);

    {
        Ptrs6 p;
        for (int j = 0; j < 6; ++j) p.p[j] = (const float*)d_in[j];
        cvt_in_kernel<<<dim3(8192, 6), 256, 0, stream>>>(p, xb);
    }
    {
        Ptrs7 p;
        for (int j = 0; j < 7; ++j) p.p[j] = (const float*)d_in[6 + j];
        cvt_w_kernel<<<dim3(32, 32, 7), dim3(32, 8), 0, stream>>>(p, wT);
    }
    {
        GemmPtrs gp;
        gp.a1[0] = xb;           gp.a1[1] = xb + NB;     gp.a1[2] = xb + 2 * NB;
        gp.a2[0] = xb + 3 * NB;  gp.a2[1] = xb + 4 * NB; gp.a2[2] = xb + 5 * NB;
        gp.b1[0] = wT;           gp.b1[1] = wT + NW;     gp.b1[2] = wT + 2 * NW;
        gp.b2[0] = wT + 3 * NW;  gp.b2[1] = wT + 4 * NW; gp.b2[2] = wT + 5 * NW;
        gp.outbh[0] = Qg; gp.outbh[1] = Kg; gp.outbh[2] = Vg;
        gemm_kernel<0><<<dim3(1536), 256, 0, stream>>>(gp, 32, 16, nullptr, nullptr, nullptr);
    }
    vt_kernel<<<dim3(32, 64), 256, 0, stream>>>(Vg, Vtg);
    attn_kernel<<<dim3(512), 512, 0, stream>>>(Qg, Kg, Vtg, ctxh);
    {
        GemmPtrs gp;
        for (int j = 0; j < 3; ++j) {
            gp.a1[j] = ctxh; gp.a2[j] = ctxh;
            gp.b1[j] = wT + 6 * NW; gp.b2[j] = wT + 6 * NW;
            gp.outbh[j] = nullptr;
        }
        gemm_kernel<1><<<dim3(512), 256, 0, stream>>>(gp, 16, 16, tmp,
                                                      (const float*)d_in[0],
                                                      (const float*)d_in[3]);
    }
    ln_kernel<<<dim3(8192), 256, 0, stream>>>(tmp, (const float*)d_in[13],
                                              (const float*)d_in[14], (float*)d_out);
}

// Round 4
// 523.567 us; speedup vs baseline: 1.3601x; 1.0181x over previous
//
#include <hip/hip_runtime.h>
#include <hip/hip_bf16.h>
#include <cstdint>
#include <cstddef>

typedef __bf16 bf16;
typedef __bf16 bf16x8 __attribute__((ext_vector_type(8)));
typedef __bf16 bf16x4v __attribute__((ext_vector_type(4)));
typedef __bf16 bf16x2v __attribute__((ext_vector_type(2)));
typedef float f32x4 __attribute__((ext_vector_type(4)));
typedef float f32x16 __attribute__((ext_vector_type(16)));
typedef unsigned uint2v __attribute__((ext_vector_type(2)));
typedef unsigned uint4v __attribute__((ext_vector_type(4)));

#define MFMA16(a, b, c) __builtin_amdgcn_mfma_f32_16x16x32_bf16((a), (b), (c), 0, 0, 0)
#define MFMA32(a, b, c) __builtin_amdgcn_mfma_f32_32x32x16_bf16((a), (b), (c), 0, 0, 0)
#define SWZ(row, byte) ((((row) * 128) + (byte)) ^ (((row) & 7) << 4))
#define GLOAD_LDS(g, l) \
    __builtin_amdgcn_global_load_lds((const __attribute__((address_space(1))) void*)(g), \
                                     (__attribute__((address_space(3))) void*)(l), 16, 0, 0)
#define VMWAIT(n) asm volatile("s_waitcnt vmcnt(" #n ")" ::: "memory")
#define LGKM0()   asm volatile("s_waitcnt lgkmcnt(0)" ::: "memory")
#define BAR()     __builtin_amdgcn_s_barrier()
#define SCHED0()  __builtin_amdgcn_sched_barrier(0)

// Problem constants
constexpr int BB = 4, SS = 2048, DD = 1024, HH = 16;
constexpr int NROWS = BB * SS;                 // 8192
constexpr size_t NB = (size_t)NROWS * DD;      // elems per [B,S,D] tensor
constexpr size_t NW = (size_t)DD * DD;         // elems per weight

static __device__ __forceinline__ unsigned pk2(float a, float b) {
    bf16x2v h;
    h[0] = (bf16)a; h[1] = (bf16)b;
    return __builtin_bit_cast(unsigned, h);
}

static __device__ __forceinline__ bf16x8 frag4(unsigned w0, unsigned w1, unsigned w2, unsigned w3) {
    uint4v u;
    u[0] = w0; u[1] = w1; u[2] = w2; u[3] = w3;
    return __builtin_bit_cast(bf16x8, u);
}

// ---------------------------------------------------------------------------
// Kernel 0a: convert 6 input tensors f32 -> bf16
// ---------------------------------------------------------------------------
struct Ptrs6 { const float* p[6]; };

__global__ __launch_bounds__(256) void cvt_in_kernel(Ptrs6 src, bf16* dst) {
    const int z = blockIdx.y;
    const size_t idx = (size_t)blockIdx.x * 256 + threadIdx.x;   // float4 index
    float4 v = ((const float4*)src.p[z])[idx];
    bf16x4v o;
    o[0] = (bf16)v.x; o[1] = (bf16)v.y; o[2] = (bf16)v.z; o[3] = (bf16)v.w;
    *(bf16x4v*)(dst + z * NB + idx * 4) = o;
}

// ---------------------------------------------------------------------------
// Kernel 0b: convert + transpose 7 weights: W[k][n] f32 -> WT[n][k] bf16
// ---------------------------------------------------------------------------
struct Ptrs7 { const float* p[7]; };

__global__ __launch_bounds__(256) void cvt_w_kernel(Ptrs7 src, bf16* dst) {
    const int z = blockIdx.z;
    const float* W = src.p[z];
    bf16* WT = dst + (size_t)z * NW;
    __shared__ float tile[32][33];
    const int tx = threadIdx.x, ty = threadIdx.y;     // (32, 8)
    const int kb = blockIdx.y * 32, nb = blockIdx.x * 32;
#pragma unroll
    for (int j = 0; j < 4; ++j)
        tile[ty + j * 8][tx] = W[(size_t)(kb + ty + j * 8) * DD + nb + tx];
    __syncthreads();
#pragma unroll
    for (int j = 0; j < 4; ++j)
        WT[(size_t)(nb + ty + j * 8) * DD + kb + tx] = (bf16)tile[tx][ty + j * 8];
}

// ---------------------------------------------------------------------------
// Kernel 0c: transpose V [bh][s][64] -> Vt [bh][64][2048]
// ---------------------------------------------------------------------------
__global__ __launch_bounds__(256) void vt_kernel(const bf16* __restrict__ V,
                                                 bf16* __restrict__ Vt) {
    const int bh = blockIdx.y;
    const int s0 = blockIdx.x * 64;
    __shared__ bf16 t[64][72];
    const int tid = threadIdx.x;
    const int row = tid >> 2, seg = tid & 3;          // 64 rows x 4 chunks of 16
    const bf16* src = V + ((size_t)bh * SS + s0 + row) * 64 + seg * 16;
    bf16x8 v0 = *(const bf16x8*)src;
    bf16x8 v1 = *(const bf16x8*)(src + 8);
#pragma unroll
    for (int j = 0; j < 8; ++j) {
        t[seg * 16 + j][row] = v0[j];
        t[seg * 16 + 8 + j][row] = v1[j];
    }
    __syncthreads();
    const int d = tid >> 2, c = (tid & 3) * 16;
    bf16x8 o0 = *(const bf16x8*)(&t[d][c]);
    bf16x8 o1 = *(const bf16x8*)(&t[d][c + 8]);
    bf16* dst = Vt + ((size_t)bh * 64 + d) * SS + s0 + c;
    *(bf16x8*)dst = o0;
    *(bf16x8*)(dst + 8) = o1;
}

// ---------------------------------------------------------------------------
// Shared pointer struct for both GEMMs
// ---------------------------------------------------------------------------
struct GemmPtrs {
    const bf16* a1[3]; const bf16* a2[3];
    const bf16* b1[3]; const bf16* b2[3];
    bf16* outbh[3];
};

// ---------------------------------------------------------------------------
// Projection GEMM: 256x256 tile, 8 waves (each a 256x32 col-strip), BK=64,
// 4 phases per K-tile with counted-vmcnt pipelining (T3+T4), T2 swizzle,
// T5 setprio. LDS 128KB double-buffered.
//
// Per-tile staging order (2 global_load_lds per phase, issued for tile t+1):
//   L0,L1 = B rows [0,128)   (phase 0)
//   L2,L3 = B rows [128,256) (phase 1)
//   L4,L5 = A rows [0,128)   (phase 2)
//   L6,L7 = A rows [128,256) (phase 3)
// Phase q of tile t ds-reads A rows [64q, 64q+64) (landed via waits below)
// and (at q=0) its wave's B cols. Wait constants (steady state):
//   p0: vmcnt(4)  guarantees t.L5 (A rows 64..127)  for p1
//   p1: vmcnt(5)  guarantees t.L6                   for p2
//   p2: vmcnt(6)  guarantees t.L7                   for p3
//   p3: vmcnt(3)  guarantees t+1.L0..L4             for next tile p0
// Never drains to 0 in the main loop.
// ---------------------------------------------------------------------------
__global__ __launch_bounds__(512, 2) void gemm256_kernel(GemmPtrs P) {
    const int tid = threadIdx.x;
    const int lane = tid & 63, w = tid >> 6;
    const int g = lane >> 4, i = lane & 15;
    const int chunk = (tid & 7) ^ ((tid >> 3) & 7);   // pre-swizzled source chunk

    // XCD swizzle: 384 blocks, 48 per XCD; works m-panel-major so one XCD's
    // 48 works = 4 m-panels x 12 n-tiles (A-panel L2 reuse).
    const int cpx = gridDim.x >> 3;
    const int work = (blockIdx.x & 7) * cpx + (blockIdx.x >> 3);
    const int mpanel = work / 12;
    const int ntile = work - mpanel * 12;
    const int z = ntile >> 2;
    const int n0 = (ntile & 3) * 256;
    const int m0 = mpanel * 256;

    const bf16* __restrict__ A1 = P.a1[z];
    const bf16* __restrict__ A2 = P.a2[z];
    const bf16* __restrict__ B1 = P.b1[z];
    const bf16* __restrict__ B2 = P.b2[z];

    __shared__ __align__(16) char smem[131072];
    // A bufs @ 0 / 32768 ; B bufs @ 65536 / 98304

    f32x4 acc[16][2];
#pragma unroll
    for (int a = 0; a < 16; ++a) { acc[a][0] = 0.0f; acc[a][1] = 0.0f; }

    auto stage = [&](char* region, const bf16* G, int rc0, int rbase, int ko) {
        GLOAD_LDS(G + (size_t)(rc0 + rbase + (tid >> 3)) * 1024 + ko + chunk * 8,
                  region + rbase * 128 + w * 1024);
    };

#define LDFRAG(base, row, byte) (*(const bf16x8*)((base) + SWZ((row), (byte))))
#define LDB_ALL(Bb) do { \
    bf_[0][0] = LDFRAG((Bb), w * 32 + i,      g * 16); \
    bf_[0][1] = LDFRAG((Bb), w * 32 + i,      64 + g * 16); \
    bf_[1][0] = LDFRAG((Bb), w * 32 + 16 + i, g * 16); \
    bf_[1][1] = LDFRAG((Bb), w * 32 + 16 + i, 64 + g * 16); } while (0)
#define LDA_PH(Ab, q) do { \
    af_[0][0] = LDFRAG((Ab), (q) * 64 + i,      g * 16); \
    af_[0][1] = LDFRAG((Ab), (q) * 64 + i,      64 + g * 16); \
    af_[1][0] = LDFRAG((Ab), (q) * 64 + 16 + i, g * 16); \
    af_[1][1] = LDFRAG((Ab), (q) * 64 + 16 + i, 64 + g * 16); \
    af_[2][0] = LDFRAG((Ab), (q) * 64 + 32 + i, g * 16); \
    af_[2][1] = LDFRAG((Ab), (q) * 64 + 32 + i, 64 + g * 16); \
    af_[3][0] = LDFRAG((Ab), (q) * 64 + 48 + i, g * 16); \
    af_[3][1] = LDFRAG((Ab), (q) * 64 + 48 + i, 64 + g * 16); } while (0)
#define MFMA_PH(q) do { \
    __builtin_amdgcn_s_setprio(1); \
    acc[(q)*4+0][0] = MFMA16(af_[0][0], bf_[0][0], acc[(q)*4+0][0]); \
    acc[(q)*4+0][0] = MFMA16(af_[0][1], bf_[0][1], acc[(q)*4+0][0]); \
    acc[(q)*4+0][1] = MFMA16(af_[0][0], bf_[1][0], acc[(q)*4+0][1]); \
    acc[(q)*4+0][1] = MFMA16(af_[0][1], bf_[1][1], acc[(q)*4+0][1]); \
    acc[(q)*4+1][0] = MFMA16(af_[1][0], bf_[0][0], acc[(q)*4+1][0]); \
    acc[(q)*4+1][0] = MFMA16(af_[1][1], bf_[0][1], acc[(q)*4+1][0]); \
    acc[(q)*4+1][1] = MFMA16(af_[1][0], bf_[1][0], acc[(q)*4+1][1]); \
    acc[(q)*4+1][1] = MFMA16(af_[1][1], bf_[1][1], acc[(q)*4+1][1]); \
    acc[(q)*4+2][0] = MFMA16(af_[2][0], bf_[0][0], acc[(q)*4+2][0]); \
    acc[(q)*4+2][0] = MFMA16(af_[2][1], bf_[0][1], acc[(q)*4+2][0]); \
    acc[(q)*4+2][1] = MFMA16(af_[2][0], bf_[1][0], acc[(q)*4+2][1]); \
    acc[(q)*4+2][1] = MFMA16(af_[2][1], bf_[1][1], acc[(q)*4+2][1]); \
    acc[(q)*4+3][0] = MFMA16(af_[3][0], bf_[0][0], acc[(q)*4+3][0]); \
    acc[(q)*4+3][0] = MFMA16(af_[3][1], bf_[0][1], acc[(q)*4+3][0]); \
    acc[(q)*4+3][1] = MFMA16(af_[3][0], bf_[1][0], acc[(q)*4+3][1]); \
    acc[(q)*4+3][1] = MFMA16(af_[3][1], bf_[1][1], acc[(q)*4+3][1]); \
    __builtin_amdgcn_s_setprio(0); } while (0)

    // ---- prologue: stage tile 0 into buf 0 (L0..L7 order) ----
    stage(smem + 65536, B1, n0, 0, 0);
    stage(smem + 65536, B1, n0, 64, 0);
    stage(smem + 65536, B1, n0, 128, 0);
    stage(smem + 65536, B1, n0, 192, 0);
    stage(smem, A1, m0, 0, 0);
    stage(smem, A1, m0, 64, 0);
    stage(smem, A1, m0, 128, 0);
    stage(smem, A1, m0, 192, 0);
    VMWAIT(3);          // L0..L4 landed (B + A rows 0..127's first half)
    BAR();

    bf16x8 bf_[2][2], af_[4][2];

    // ---- main loop: tiles 0..30, staging tile t+1 ----
    for (int t = 0; t < 31; ++t) {
        const int cur = t & 1;
        char* Ab = smem + cur * 32768;
        char* Bb = smem + 65536 + cur * 32768;
        char* An_ = smem + (cur ^ 1) * 32768;
        char* Bn_ = smem + 65536 + (cur ^ 1) * 32768;
        const int ts = t + 1;
        const bf16* Ag; const bf16* Bg; int ko;
        if (ts < 16) { Ag = A1; Bg = B1; ko = ts * 64; }
        else         { Ag = A2; Bg = B2; ko = (ts - 16) * 64; }

        // phase 0
        LDB_ALL(Bb);
        LDA_PH(Ab, 0);
        stage(Bn_, Bg, n0, 0, ko);
        stage(Bn_, Bg, n0, 64, ko);
        VMWAIT(4); BAR(); LGKM0(); SCHED0();
        MFMA_PH(0);
        BAR();
        // phase 1
        LDA_PH(Ab, 1);
        stage(Bn_, Bg, n0, 128, ko);
        stage(Bn_, Bg, n0, 192, ko);
        VMWAIT(5); BAR(); LGKM0(); SCHED0();
        MFMA_PH(1);
        BAR();
        // phase 2
        LDA_PH(Ab, 2);
        stage(An_, Ag, m0, 0, ko);
        stage(An_, Ag, m0, 64, ko);
        VMWAIT(6); BAR(); LGKM0(); SCHED0();
        MFMA_PH(2);
        BAR();
        // phase 3
        LDA_PH(Ab, 3);
        stage(An_, Ag, m0, 128, ko);
        stage(An_, Ag, m0, 192, ko);
        VMWAIT(3); BAR(); LGKM0(); SCHED0();
        MFMA_PH(3);
        BAR();
    }

    // ---- epilogue: tile 31 (cur = 1), no staging; waits 2/1/0 ----
    {
        char* Ab = smem + 32768;
        char* Bb = smem + 65536 + 32768;
        LDB_ALL(Bb);
        LDA_PH(Ab, 0);
        VMWAIT(2); BAR(); LGKM0(); SCHED0();
        MFMA_PH(0);
        BAR();
        LDA_PH(Ab, 1);
        VMWAIT(1); BAR(); LGKM0(); SCHED0();
        MFMA_PH(1);
        BAR();
        LDA_PH(Ab, 2);
        VMWAIT(0); BAR(); LGKM0(); SCHED0();
        MFMA_PH(2);
        BAR();
        LDA_PH(Ab, 3);
        LGKM0(); SCHED0();
        MFMA_PH(3);
    }

    // ---- epilogue store: head layout [b,h,s,64] ----
    bf16* outQ = P.outbh[z];
#pragma unroll
    for (int mt = 0; mt < 16; ++mt) {
#pragma unroll
        for (int nt = 0; nt < 2; ++nt) {
            int c = n0 + w * 32 + nt * 16 + i;
            int h = c >> 6, d = c & 63;
#pragma unroll
            for (int r = 0; r < 4; ++r) {
                int rowg = m0 + mt * 16 + g * 4 + r;
                int b = rowg >> 11, s = rowg & 2047;
                outQ[(((size_t)(b * HH + h)) * SS + s) * 64 + d] = (bf16)acc[mt][nt][r];
            }
        }
    }
#undef LDFRAG
#undef LDB_ALL
#undef LDA_PH
#undef MFMA_PH
}

// ---------------------------------------------------------------------------
// fc GEMM (old 128x128 structure, MODE 1 only): A = head-major ctxh,
// out f32 tmp = acc + r1 + r2.
// ---------------------------------------------------------------------------
template <int MODE>
__global__ __launch_bounds__(256) void gemm_kernel(GemmPtrs P, int iters, int split,
                                                   float* outF, const float* r1, const float* r2) {
    const int cpx = gridDim.x >> 3;
    const int bid0 = blockIdx.x;
    const int work = (bid0 & 7) * cpx + (bid0 >> 3);
    const int z = work >> 9;
    const int rem = work & 511;
    const int m0 = (rem >> 3) * 128, n0 = (rem & 7) * 128;

    const bf16* __restrict__ A1 = P.a1[z];
    const bf16* __restrict__ A2 = P.a2[z];
    const bf16* __restrict__ B1 = P.b1[z];
    const bf16* __restrict__ B2 = P.b2[z];

    const int tid = threadIdx.x;
    const int lane = tid & 63, w = tid >> 6;
    const int g = lane >> 4, i = lane & 15;
    const int mb = (w >> 1) * 64, nb = (w & 1) * 64;

    __shared__ __align__(16) bf16 As[128 * 64];
    __shared__ __align__(16) bf16 Bs[128 * 64];

    const int lrow = lane >> 3, lseg = lane & 7;
    const int chunk = lseg ^ lrow;

    f32x4 acc[4][4];
#pragma unroll
    for (int aa = 0; aa < 4; ++aa)
#pragma unroll
        for (int bb = 0; bb < 4; ++bb) acc[aa][bb] = 0.0f;

    for (int kt = 0; kt < iters; ++kt) {
        const bf16* Ag; const bf16* Bg; int koff;
        if (kt < split) { Ag = A1; Bg = B1; koff = kt * 64; }
        else            { Ag = A2; Bg = B2; koff = (kt - split) * 64; }

        __syncthreads();
#pragma unroll
        for (int c = 0; c < 4; ++c) {
            const int row = (w * 4 + c) * 8 + lrow;
            const bf16* ap;
            if (MODE == 0) {
                ap = Ag + (size_t)(m0 + row) * DD + koff + chunk * 8;
            } else {
                int gr = m0 + row;
                ap = Ag + ((size_t)((gr >> 11) * HH + (koff >> 6)) * SS + (gr & 2047)) * 64 + chunk * 8;
            }
            const bf16* bp = Bg + (size_t)(n0 + row) * DD + koff + chunk * 8;
            GLOAD_LDS(ap, As + (w * 4 + c) * 512);
            GLOAD_LDS(bp, Bs + (w * 4 + c) * 512);
        }
        __syncthreads();

#pragma unroll
        for (int f = 0; f < 2; ++f) {
            bf16x8 af[4], bff[4];
#pragma unroll
            for (int mt = 0; mt < 4; ++mt) {
                int row = mb + mt * 16 + i;
                af[mt] = *(const bf16x8*)((char*)As + SWZ(row, f * 64 + g * 16));
            }
#pragma unroll
            for (int nt = 0; nt < 4; ++nt) {
                int row = nb + nt * 16 + i;
                bff[nt] = *(const bf16x8*)((char*)Bs + SWZ(row, f * 64 + g * 16));
            }
#pragma unroll
            for (int mt = 0; mt < 4; ++mt)
#pragma unroll
                for (int nt = 0; nt < 4; ++nt)
                    acc[mt][nt] = MFMA16(af[mt], bff[nt], acc[mt][nt]);
        }
    }

    if (MODE == 0) {
        bf16* outQ = P.outbh[z];
#pragma unroll
        for (int mt = 0; mt < 4; ++mt)
#pragma unroll
            for (int nt = 0; nt < 4; ++nt) {
                int colg = n0 + nb + nt * 16 + i;
                int h = colg >> 6, d = colg & 63;
#pragma unroll
                for (int r = 0; r < 4; ++r) {
                    int rowg = m0 + mb + mt * 16 + g * 4 + r;
                    int b = rowg >> 11, s = rowg & 2047;
                    outQ[(((size_t)(b * HH + h)) * SS + s) * 64 + d] = (bf16)acc[mt][nt][r];
                }
            }
    } else {
#pragma unroll
        for (int mt = 0; mt < 4; ++mt)
#pragma unroll
            for (int nt = 0; nt < 4; ++nt) {
                int colg = n0 + nb + nt * 16 + i;
#pragma unroll
                for (int r = 0; r < 4; ++r) {
                    int rowg = m0 + mb + mt * 16 + g * 4 + r;
                    size_t off = (size_t)rowg * DD + colg;
                    outF[off] = acc[mt][nt][r] + r1[off] + r2[off];
                }
            }
    }
}

// ---------------------------------------------------------------------------
// Flash attention: 8 waves x 32 queries, KVBLK=64, swapped QK^T and PV.
// Q/K: [bh][2048][64] bf16;  Vt: [bh][64][2048] bf16;  ctxh: [bh][2048][64].
// Each lane owns one query row (q = lane&31); softmax fully in registers.
// ---------------------------------------------------------------------------
__global__ __launch_bounds__(512, 4) void attn_kernel(const bf16* __restrict__ Qg,
                                                      const bf16* __restrict__ Kg,
                                                      const bf16* __restrict__ Vt,
                                                      bf16* __restrict__ ctxh) {
    const int bid = blockIdx.x;
    const int bh = ((bid & 7) << 3) | (bid >> 6);
    const int qt = (bid >> 3) & 7;

    const int tid = threadIdx.x;
    const int lane = tid & 63, w = tid >> 6;
    const int hi = lane >> 5, q = lane & 31;

    __shared__ __align__(16) char smem[32768];

    const int qrow = qt * 256 + w * 32 + q;
    bf16x8 qf[4];
    {
        const bf16* qp = Qg + ((size_t)bh * SS + qrow) * 64;
#pragma unroll
        for (int c = 0; c < 4; ++c) {
            bf16x8 v = *(const bf16x8*)(qp + c * 16 + hi * 8);
#pragma unroll
            for (int e = 0; e < 8; ++e) v[e] = (bf16)((float)v[e] * 0.0625f);
            qf[c] = v;
        }
    }

    const int srow = tid >> 3, sseg = tid & 7;
    const bf16* kgp = Kg + (size_t)bh * SS * 64;
    const bf16* vgp = Vt + (size_t)bh * 64 * SS;
    const int sbyte = SWZ(srow, sseg * 16);

    bf16x8 kreg = *(const bf16x8*)(kgp + (size_t)srow * 64 + sseg * 8);
    bf16x8 vreg = *(const bf16x8*)(vgp + (size_t)srow * SS + sseg * 8);

    f32x16 o0 = {}, o1 = {};
    float m = -3e38f, l = 0.0f;

    for (int kt = 0; kt < SS / 64; ++kt) {
        char* kb_ = smem + (kt & 1) * 16384;
        char* vb_ = kb_ + 8192;
        *(bf16x8*)(kb_ + sbyte) = kreg;
        *(bf16x8*)(vb_ + sbyte) = vreg;
        if (kt + 1 < SS / 64) {
            const int k0n = (kt + 1) * 64;
            kreg = *(const bf16x8*)(kgp + (size_t)(k0n + srow) * 64 + sseg * 8);
            vreg = *(const bf16x8*)(vgp + (size_t)srow * SS + k0n + sseg * 8);
        }
        __syncthreads();

        f32x16 st0 = {}, st1 = {};
        __builtin_amdgcn_s_setprio(1);
#pragma unroll
        for (int c = 0; c < 4; ++c) {
            bf16x8 kf = *(const bf16x8*)(kb_ + SWZ(q, c * 32 + hi * 16));
            st0 = MFMA32(kf, qf[c], st0);
        }
#pragma unroll
        for (int c = 0; c < 4; ++c) {
            bf16x8 kf = *(const bf16x8*)(kb_ + SWZ(32 + q, c * 32 + hi * 16));
            st1 = MFMA32(kf, qf[c], st1);
        }
        __builtin_amdgcn_s_setprio(0);

        float tm = st0[0];
#pragma unroll
        for (int r = 1; r < 16; ++r) tm = fmaxf(tm, st0[r]);
#pragma unroll
        for (int r = 0; r < 16; ++r) tm = fmaxf(tm, st1[r]);
        tm = fmaxf(tm, __shfl_xor(tm, 32, 64));
        if (!__all(tm - m <= 8.0f)) {
            float nm = fmaxf(m, tm);
            float al = __expf(m - nm);
            l *= al;
            o0 *= al;
            o1 *= al;
            m = nm;
        }
        float sum = 0.0f;
#pragma unroll
        for (int r = 0; r < 16; ++r) { st0[r] = __expf(st0[r] - m); sum += st0[r]; }
#pragma unroll
        for (int r = 0; r < 16; ++r) { st1[r] = __expf(st1[r] - m); sum += st1[r]; }
        l += sum;

        bf16x8 pf[4];
#pragma unroll
        for (int c = 0; c < 4; ++c) {
            const f32x16 s_ = (c < 2) ? st0 : st1;
            const int b0 = (c & 1) * 8;
            unsigned a0 = pk2(s_[b0 + 0], s_[b0 + 1]);
            unsigned c0 = pk2(s_[b0 + 4], s_[b0 + 5]);
            unsigned a1 = pk2(s_[b0 + 2], s_[b0 + 3]);
            unsigned c1 = pk2(s_[b0 + 6], s_[b0 + 7]);
            uint2v s1 = __builtin_amdgcn_permlane32_swap(a0, c0, false, false);
            uint2v s2 = __builtin_amdgcn_permlane32_swap(a1, c1, false, false);
            pf[c] = frag4(s1[0], s2[0], s1[1], s2[1]);
        }

        __builtin_amdgcn_s_setprio(1);
#pragma unroll
        for (int c = 0; c < 4; ++c) {
            bf16x8 vf = *(const bf16x8*)(vb_ + SWZ(q, c * 32 + hi * 16));
            o0 = MFMA32(vf, pf[c], o0);
        }
#pragma unroll
        for (int c = 0; c < 4; ++c) {
            bf16x8 vf = *(const bf16x8*)(vb_ + SWZ(32 + q, c * 32 + hi * 16));
            o1 = MFMA32(vf, pf[c], o1);
        }
        __builtin_amdgcn_s_setprio(0);
    }

    float lt = l + __shfl_xor(l, 32, 64);
    float rl = 1.0f / lt;
    __syncthreads();
    const int orow = w * 32 + q;
#pragma unroll
    for (int dh = 0; dh < 2; ++dh) {
#pragma unroll
        for (int r = 0; r < 16; r += 2) {
            float v0 = (dh ? o1[r] : o0[r]) * rl;
            float v1 = (dh ? o1[r + 1] : o0[r + 1]) * rl;
            int d = dh * 32 + (r & 3) + 8 * (r >> 2) + 4 * hi;
            *(unsigned*)(smem + SWZ(orow, d * 2)) = pk2(v0, v1);
        }
    }
    __syncthreads();
    {
        const int row = tid >> 1, hf = tid & 1;
        bf16* outp = ctxh + ((size_t)bh * SS + qt * 256 + row) * 64 + hf * 32;
#pragma unroll
        for (int c = 0; c < 4; ++c) {
            bf16x8 v = *(const bf16x8*)(smem + SWZ(row, hf * 64 + c * 16));
            *(bf16x8*)(outp + c * 8) = v;
        }
    }
}

// ---------------------------------------------------------------------------
// LayerNorm: one row (1024) per block of 256 threads.
// ---------------------------------------------------------------------------
__global__ __launch_bounds__(256) void ln_kernel(const float* __restrict__ tmp,
                                                 const float* __restrict__ gamma,
                                                 const float* __restrict__ beta,
                                                 float* __restrict__ out) {
    const int row = blockIdx.x;
    const int t = threadIdx.x;
    float4 v = ((const float4*)(tmp + (size_t)row * DD))[t];
    float s = v.x + v.y + v.z + v.w;
    float ss = v.x * v.x + v.y * v.y + v.z * v.z + v.w * v.w;
#pragma unroll
    for (int mask = 1; mask <= 32; mask <<= 1) {
        s += __shfl_xor(s, mask, 64);
        ss += __shfl_xor(ss, mask, 64);
    }
    __shared__ float red[8];
    const int w = t >> 6, lane = t & 63;
    if (lane == 0) { red[w] = s; red[4 + w] = ss; }
    __syncthreads();
    s = red[0] + red[1] + red[2] + red[3];
    ss = red[4] + red[5] + red[6] + red[7];
    const float mu = s * (1.0f / 1024.0f);
    const float var = ss * (1.0f / 1024.0f) - mu * mu;
    const float rs = rsqrtf(var + 1e-6f);
    float4 gm = ((const float4*)gamma)[t];
    float4 bt = ((const float4*)beta)[t];
    float4 ov;
    ov.x = (v.x - mu) * rs * gm.x + bt.x;
    ov.y = (v.y - mu) * rs * gm.y + bt.y;
    ov.z = (v.z - mu) * rs * gm.z + bt.z;
    ov.w = (v.w - mu) * rs * gm.w + bt.w;
    ((float4*)(out + (size_t)row * DD))[t] = ov;
}

// ---------------------------------------------------------------------------
// Launcher
// ---------------------------------------------------------------------------
extern "C" void kernel_launch(void* const* d_in, const int* in_sizes, int n_in,
                              void* d_out, int out_size, void* d_ws, size_t ws_size,
                              hipStream_t stream) {
    (void)in_sizes; (void)n_in; (void)out_size; (void)ws_size;

    char* ws = (char*)d_ws;
    bf16* xb = (bf16*)ws;
    bf16* wT = (bf16*)(ws + 100663296ull);
    bf16* Qg = (bf16*)(ws + 115343360ull);
    bf16* Kg = (bf16*)(ws + 132120576ull);
    bf16* Vg = (bf16*)(ws + 148897792ull);
    bf16* ctxh = (bf16*)ws;
    bf16* Vtg = (bf16*)(ws + 16777216ull);
    float* tmp = (float*)(ws + 33554432ull);

    {
        Ptrs6 p;
        for (int j = 0; j < 6; ++j) p.p[j] = (const float*)d_in[j];
        cvt_in_kernel<<<dim3(8192, 6), 256, 0, stream>>>(p, xb);
    }
    {
        Ptrs7 p;
        for (int j = 0; j < 7; ++j) p.p[j] = (const float*)d_in[6 + j];
        cvt_w_kernel<<<dim3(32, 32, 7), dim3(32, 8), 0, stream>>>(p, wT);
    }
    {
        GemmPtrs gp;
        gp.a1[0] = xb;           gp.a1[1] = xb + NB;     gp.a1[2] = xb + 2 * NB;
        gp.a2[0] = xb + 3 * NB;  gp.a2[1] = xb + 4 * NB; gp.a2[2] = xb + 5 * NB;
        gp.b1[0] = wT;           gp.b1[1] = wT + NW;     gp.b1[2] = wT + 2 * NW;
        gp.b2[0] = wT + 3 * NW;  gp.b2[1] = wT + 4 * NW; gp.b2[2] = wT + 5 * NW;
        gp.outbh[0] = Qg; gp.outbh[1] = Kg; gp.outbh[2] = Vg;
        gemm256_kernel<<<dim3(384), 512, 0, stream>>>(gp);
    }
    vt_kernel<<<dim3(32, 64), 256, 0, stream>>>(Vg, Vtg);
    attn_kernel<<<dim3(512), 512, 0, stream>>>(Qg, Kg, Vtg, ctxh);
    {
        GemmPtrs gp;
        for (int j = 0; j < 3; ++j) {
            gp.a1[j] = ctxh; gp.a2[j] = ctxh;
            gp.b1[j] = wT + 6 * NW; gp.b2[j] = wT + 6 * NW;
            gp.outbh[j] = nullptr;
        }
        gemm_kernel<1><<<dim3(512), 256, 0, stream>>>(gp, 16, 16, tmp,
                                                      (const float*)d_in[0],
                                                      (const float*)d_in[3]);
    }
    ln_kernel<<<dim3(8192), 256, 0, stream>>>(tmp, (const float*)d_in[13],
                                              (const float*)d_in[14], (float*)d_out);
}

// Round 5
// 511.550 us; speedup vs baseline: 1.3921x; 1.0235x over previous
//
#include <hip/hip_runtime.h>
#include <hip/hip_bf16.h>
#include <cstdint>
#include <cstddef>

typedef __bf16 bf16;
typedef __bf16 bf16x8 __attribute__((ext_vector_type(8)));
typedef __bf16 bf16x4v __attribute__((ext_vector_type(4)));
typedef __bf16 bf16x2v __attribute__((ext_vector_type(2)));
typedef float f32x4 __attribute__((ext_vector_type(4)));
typedef float f32x16 __attribute__((ext_vector_type(16)));
typedef unsigned uint2v __attribute__((ext_vector_type(2)));
typedef unsigned uint4v __attribute__((ext_vector_type(4)));

#define MFMA16(a, b, c) __builtin_amdgcn_mfma_f32_16x16x32_bf16((a), (b), (c), 0, 0, 0)
#define MFMA32(a, b, c) __builtin_amdgcn_mfma_f32_32x32x16_bf16((a), (b), (c), 0, 0, 0)
#define SWZ(row, byte) ((((row) * 128) + (byte)) ^ (((row) & 7) << 4))
#define GLOAD_LDS(g, l) \
    __builtin_amdgcn_global_load_lds((const __attribute__((address_space(1))) void*)(g), \
                                     (__attribute__((address_space(3))) void*)(l), 16, 0, 0)
#define VMWAIT(n) asm volatile("s_waitcnt vmcnt(" #n ")" ::: "memory")
#define LGKM0()   asm volatile("s_waitcnt lgkmcnt(0)" ::: "memory")
#define BAR()     __builtin_amdgcn_s_barrier()
#define SCHED0()  __builtin_amdgcn_sched_barrier(0)

// Problem constants
constexpr int BB = 4, SS = 2048, DD = 1024, HH = 16;
constexpr int NROWS = BB * SS;                 // 8192
constexpr size_t NB = (size_t)NROWS * DD;      // elems per [B,S,D] tensor
constexpr size_t NW = (size_t)DD * DD;         // elems per weight

static __device__ __forceinline__ unsigned pk2(float a, float b) {
    bf16x2v h;
    h[0] = (bf16)a; h[1] = (bf16)b;
    return __builtin_bit_cast(unsigned, h);
}

static __device__ __forceinline__ bf16x8 frag4(unsigned w0, unsigned w1, unsigned w2, unsigned w3) {
    uint4v u;
    u[0] = w0; u[1] = w1; u[2] = w2; u[3] = w3;
    return __builtin_bit_cast(bf16x8, u);
}

// ---------------------------------------------------------------------------
// Kernel 0a: convert 6 input tensors f32 -> bf16
// ---------------------------------------------------------------------------
struct Ptrs6 { const float* p[6]; };

__global__ __launch_bounds__(256) void cvt_in_kernel(Ptrs6 src, bf16* dst) {
    const int z = blockIdx.y;
    const size_t idx = (size_t)blockIdx.x * 256 + threadIdx.x;   // float4 index
    float4 v = ((const float4*)src.p[z])[idx];
    bf16x4v o;
    o[0] = (bf16)v.x; o[1] = (bf16)v.y; o[2] = (bf16)v.z; o[3] = (bf16)v.w;
    *(bf16x4v*)(dst + z * NB + idx * 4) = o;
}

// ---------------------------------------------------------------------------
// Kernel 0b: convert + transpose 7 weights: W[k][n] f32 -> WT[n][k] bf16
// ---------------------------------------------------------------------------
struct Ptrs7 { const float* p[7]; };

__global__ __launch_bounds__(256) void cvt_w_kernel(Ptrs7 src, bf16* dst) {
    const int z = blockIdx.z;
    const float* W = src.p[z];
    bf16* WT = dst + (size_t)z * NW;
    __shared__ float tile[32][33];
    const int tx = threadIdx.x, ty = threadIdx.y;     // (32, 8)
    const int kb = blockIdx.y * 32, nb = blockIdx.x * 32;
#pragma unroll
    for (int j = 0; j < 4; ++j)
        tile[ty + j * 8][tx] = W[(size_t)(kb + ty + j * 8) * DD + nb + tx];
    __syncthreads();
#pragma unroll
    for (int j = 0; j < 4; ++j)
        WT[(size_t)(nb + ty + j * 8) * DD + kb + tx] = (bf16)tile[tx][ty + j * 8];
}

// ---------------------------------------------------------------------------
// Kernel 0c: transpose V [bh][s][64] -> Vt [bh][64][2048]
// ---------------------------------------------------------------------------
__global__ __launch_bounds__(256) void vt_kernel(const bf16* __restrict__ V,
                                                 bf16* __restrict__ Vt) {
    const int bh = blockIdx.y;
    const int s0 = blockIdx.x * 64;
    __shared__ bf16 t[64][72];
    const int tid = threadIdx.x;
    const int row = tid >> 2, seg = tid & 3;          // 64 rows x 4 chunks of 16
    const bf16* src = V + ((size_t)bh * SS + s0 + row) * 64 + seg * 16;
    bf16x8 v0 = *(const bf16x8*)src;
    bf16x8 v1 = *(const bf16x8*)(src + 8);
#pragma unroll
    for (int j = 0; j < 8; ++j) {
        t[seg * 16 + j][row] = v0[j];
        t[seg * 16 + 8 + j][row] = v1[j];
    }
    __syncthreads();
    const int d = tid >> 2, c = (tid & 3) * 16;
    bf16x8 o0 = *(const bf16x8*)(&t[d][c]);
    bf16x8 o1 = *(const bf16x8*)(&t[d][c + 8]);
    bf16* dst = Vt + ((size_t)bh * 64 + d) * SS + s0 + c;
    *(bf16x8*)dst = o0;
    *(bf16x8*)(dst + 8) = o1;
}

// ---------------------------------------------------------------------------
// Shared pointer struct for both GEMMs
// ---------------------------------------------------------------------------
struct GemmPtrs {
    const bf16* a1[3]; const bf16* a2[3];
    const bf16* b1[3]; const bf16* b2[3];
    bf16* outbh[3];
};

// ---------------------------------------------------------------------------
// Deep-pipelined GEMM: tile 256x128, BK=64, 512 threads (8 waves as 4Mx2N,
// each 64x64). Triple-buffered LDS (3 x 48KB), staging issued TWO K-tiles
// ahead (6 global_load_lds calls at phase 0), one counted VMWAIT(6) per
// K-tile at phase 1 -- never drains to 0 in the main loop (T3+T4). T2
// swizzle via pre-swizzled global source + linear LDS dest (rule 21).
//
// Wait ledger (6 calls/tile):
//   prologue: stage t0, t1 (12 in flight); VMWAIT(6) -> t0 landed; BAR
//   iter t ph0: issue t+2's 6 calls (<=12 in flight); reads tile t (safe:
//               guaranteed by previous iteration's ph1 wait)
//   iter t ph1: VMWAIT(6) -> only t+2's calls remain -> t+1 fully landed
//   epilogue: VMWAIT(0) before last tile.
//
// MODE 0 (proj): A row-major [8192][1024]; out bf16 head layout [bh][s][64]
// MODE 1 (fc):   A head-major ctxh [bh][s][64]; out f32 = acc + r1 + r2
// NNT = total n-tiles (24 proj / 8 fc); z = nt>>3 selects tensor triple.
// ---------------------------------------------------------------------------
template <int MODE, int NNT>
__global__ __launch_bounds__(512, 2) void gemm_dp_kernel(GemmPtrs P, int iters, int split,
                                                         float* outF, const float* r1,
                                                         const float* r2) {
    const int tid = threadIdx.x;
    const int lane = tid & 63, w = tid >> 6;
    const int g = lane >> 4, i = lane & 15;
    const int chunk = (tid & 7) ^ ((tid >> 3) & 7);   // pre-swizzled source chunk
    const int mw = w >> 1, nw = w & 1;

    // XCD swizzle (grid % 8 == 0): mpanel-major work order -> A panels L2-hot
    const int cpx = gridDim.x >> 3;
    const int work = (blockIdx.x & 7) * cpx + (blockIdx.x >> 3);
    const int mpanel = work / NNT;
    const int nt = work - mpanel * NNT;
    const int z = nt >> 3;
    const int n0 = (nt & 7) * 128;        // col within this z's 1024
    const int m0 = mpanel * 256;

    const bf16* __restrict__ A1 = P.a1[z];
    const bf16* __restrict__ A2 = P.a2[z];
    const bf16* __restrict__ B1 = P.b1[z];
    const bf16* __restrict__ B2 = P.b2[z];

    __shared__ __align__(16) char smem[147456];   // 3 x (A 32KB @0 + B 16KB @32768)

    f32x4 acc[4][4];
#pragma unroll
    for (int a = 0; a < 4; ++a)
#pragma unroll
        for (int b = 0; b < 4; ++b) acc[a][b] = 0.0f;

    // one stage call = 64 rows x 128B (8 waves x 8 rows), linear LDS dest
    auto stageA = [&](char* buf, const bf16* Ag, int rbase, int ko) {
        const int gr = m0 + rbase + (tid >> 3);
        const bf16* ap;
        if (MODE == 0) {
            ap = Ag + (size_t)gr * 1024 + ko + chunk * 8;
        } else {
            ap = Ag + ((size_t)((gr >> 11) * HH + (ko >> 6)) * SS + (gr & 2047)) * 64 + chunk * 8;
        }
        GLOAD_LDS(ap, buf + rbase * 128 + w * 1024);
    };
    auto stageB = [&](char* buf, const bf16* Bg, int rbase, int ko) {
        const bf16* bp = Bg + (size_t)(n0 + rbase + (tid >> 3)) * 1024 + ko + chunk * 8;
        GLOAD_LDS(bp, buf + 32768 + rbase * 128 + w * 1024);
    };
    auto stage_tile = [&](int ts, char* buf) {
        const bf16* Ag; const bf16* Bg; int ko;
        if (ts < split) { Ag = A1; Bg = B1; ko = ts * 64; }
        else            { Ag = A2; Bg = B2; ko = (ts - split) * 64; }
        stageA(buf, Ag, 0, ko);
        stageA(buf, Ag, 64, ko);
        stageA(buf, Ag, 128, ko);
        stageA(buf, Ag, 192, ko);
        stageB(buf, Bg, 0, ko);
        stageB(buf, Bg, 64, ko);
    };

    bf16x8 af_[4], bf_[4];

#define LDFRAGS(bufc, kf) do { \
    char* Ab_ = (bufc); char* Bb_ = (bufc) + 32768; \
    af_[0] = *(const bf16x8*)(Ab_ + SWZ(mw * 64 +  0 + i, (kf) * 64 + g * 16)); \
    af_[1] = *(const bf16x8*)(Ab_ + SWZ(mw * 64 + 16 + i, (kf) * 64 + g * 16)); \
    af_[2] = *(const bf16x8*)(Ab_ + SWZ(mw * 64 + 32 + i, (kf) * 64 + g * 16)); \
    af_[3] = *(const bf16x8*)(Ab_ + SWZ(mw * 64 + 48 + i, (kf) * 64 + g * 16)); \
    bf_[0] = *(const bf16x8*)(Bb_ + SWZ(nw * 64 +  0 + i, (kf) * 64 + g * 16)); \
    bf_[1] = *(const bf16x8*)(Bb_ + SWZ(nw * 64 + 16 + i, (kf) * 64 + g * 16)); \
    bf_[2] = *(const bf16x8*)(Bb_ + SWZ(nw * 64 + 32 + i, (kf) * 64 + g * 16)); \
    bf_[3] = *(const bf16x8*)(Bb_ + SWZ(nw * 64 + 48 + i, (kf) * 64 + g * 16)); \
} while (0)

#define DO_MFMA() do { \
    __builtin_amdgcn_s_setprio(1); \
    _Pragma("unroll") \
    for (int mt = 0; mt < 4; ++mt) \
        _Pragma("unroll") \
        for (int nn = 0; nn < 4; ++nn) \
            acc[mt][nn] = MFMA16(af_[mt], bf_[nn], acc[mt][nn]); \
    __builtin_amdgcn_s_setprio(0); \
} while (0)

    // ---- prologue ----
    stage_tile(0, smem);
    stage_tile(1, smem + 49152);
    VMWAIT(6);           // tile 0 landed
    BAR();

    int bufsel = 0, stagesel = 2;
    for (int t = 0; t < iters - 2; ++t) {
        char* buf = smem + bufsel * 49152;
        // phase 0
        LDFRAGS(buf, 0);
        stage_tile(t + 2, smem + stagesel * 49152);
        BAR(); LGKM0(); SCHED0();
        DO_MFMA();
        BAR();
        // phase 1
        LDFRAGS(buf, 1);
        VMWAIT(6);       // tile t+1 landed (only t+2's 6 calls remain)
        BAR(); LGKM0(); SCHED0();
        DO_MFMA();
        BAR();
        bufsel = (bufsel == 2) ? 0 : bufsel + 1;
        stagesel = (stagesel == 2) ? 0 : stagesel + 1;
    }
    // ---- epilogue: tile iters-2 (drain to 0), then tile iters-1 ----
    {
        char* buf = smem + bufsel * 49152;
        LDFRAGS(buf, 0);
        BAR(); LGKM0(); SCHED0();
        DO_MFMA();
        BAR();
        LDFRAGS(buf, 1);
        VMWAIT(0);       // last tile landed
        BAR(); LGKM0(); SCHED0();
        DO_MFMA();
        BAR();
        bufsel = (bufsel == 2) ? 0 : bufsel + 1;
    }
    {
        char* buf = smem + bufsel * 49152;
        LDFRAGS(buf, 0);
        BAR(); LGKM0(); SCHED0();
        DO_MFMA();
        BAR();
        LDFRAGS(buf, 1);
        LGKM0(); SCHED0();
        DO_MFMA();
    }
#undef LDFRAGS
#undef DO_MFMA

    // ---- epilogue store ----
    if (MODE == 0) {
        bf16* outQ = P.outbh[z];
#pragma unroll
        for (int mt = 0; mt < 4; ++mt)
#pragma unroll
            for (int nn = 0; nn < 4; ++nn) {
                int c = n0 + nw * 64 + nn * 16 + i;
                int h = c >> 6, d = c & 63;
#pragma unroll
                for (int r = 0; r < 4; ++r) {
                    int rowg = m0 + mw * 64 + mt * 16 + g * 4 + r;
                    int b = rowg >> 11, s = rowg & 2047;
                    outQ[(((size_t)(b * HH + h)) * SS + s) * 64 + d] = (bf16)acc[mt][nn][r];
                }
            }
    } else {
#pragma unroll
        for (int mt = 0; mt < 4; ++mt)
#pragma unroll
            for (int nn = 0; nn < 4; ++nn) {
                int colg = n0 + nw * 64 + nn * 16 + i;
#pragma unroll
                for (int r = 0; r < 4; ++r) {
                    int rowg = m0 + mw * 64 + mt * 16 + g * 4 + r;
                    size_t off = (size_t)rowg * DD + colg;
                    outF[off] = acc[mt][nn][r] + r1[off] + r2[off];
                }
            }
    }
}

// ---------------------------------------------------------------------------
// Flash attention: 8 waves x 32 queries, KVBLK=64, swapped QK^T and PV.
// Q/K: [bh][2048][64] bf16;  Vt: [bh][64][2048] bf16;  ctxh: [bh][2048][64].
// Each lane owns one query row (q = lane&31); softmax fully in registers.
// ---------------------------------------------------------------------------
__global__ __launch_bounds__(512, 4) void attn_kernel(const bf16* __restrict__ Qg,
                                                      const bf16* __restrict__ Kg,
                                                      const bf16* __restrict__ Vt,
                                                      bf16* __restrict__ ctxh) {
    const int bid = blockIdx.x;
    const int bh = ((bid & 7) << 3) | (bid >> 6);
    const int qt = (bid >> 3) & 7;

    const int tid = threadIdx.x;
    const int lane = tid & 63, w = tid >> 6;
    const int hi = lane >> 5, q = lane & 31;

    __shared__ __align__(16) char smem[32768];

    const int qrow = qt * 256 + w * 32 + q;
    bf16x8 qf[4];
    {
        const bf16* qp = Qg + ((size_t)bh * SS + qrow) * 64;
#pragma unroll
        for (int c = 0; c < 4; ++c) {
            bf16x8 v = *(const bf16x8*)(qp + c * 16 + hi * 8);
#pragma unroll
            for (int e = 0; e < 8; ++e) v[e] = (bf16)((float)v[e] * 0.0625f);
            qf[c] = v;
        }
    }

    const int srow = tid >> 3, sseg = tid & 7;
    const bf16* kgp = Kg + (size_t)bh * SS * 64;
    const bf16* vgp = Vt + (size_t)bh * 64 * SS;
    const int sbyte = SWZ(srow, sseg * 16);

    bf16x8 kreg = *(const bf16x8*)(kgp + (size_t)srow * 64 + sseg * 8);
    bf16x8 vreg = *(const bf16x8*)(vgp + (size_t)srow * SS + sseg * 8);

    f32x16 o0 = {}, o1 = {};
    float m = -3e38f, l = 0.0f;

    for (int kt = 0; kt < SS / 64; ++kt) {
        char* kb_ = smem + (kt & 1) * 16384;
        char* vb_ = kb_ + 8192;
        *(bf16x8*)(kb_ + sbyte) = kreg;
        *(bf16x8*)(vb_ + sbyte) = vreg;
        if (kt + 1 < SS / 64) {
            const int k0n = (kt + 1) * 64;
            kreg = *(const bf16x8*)(kgp + (size_t)(k0n + srow) * 64 + sseg * 8);
            vreg = *(const bf16x8*)(vgp + (size_t)srow * SS + k0n + sseg * 8);
        }
        __syncthreads();

        f32x16 st0 = {}, st1 = {};
        __builtin_amdgcn_s_setprio(1);
#pragma unroll
        for (int c = 0; c < 4; ++c) {
            bf16x8 kf = *(const bf16x8*)(kb_ + SWZ(q, c * 32 + hi * 16));
            st0 = MFMA32(kf, qf[c], st0);
        }
#pragma unroll
        for (int c = 0; c < 4; ++c) {
            bf16x8 kf = *(const bf16x8*)(kb_ + SWZ(32 + q, c * 32 + hi * 16));
            st1 = MFMA32(kf, qf[c], st1);
        }
        __builtin_amdgcn_s_setprio(0);

        float tm = st0[0];
#pragma unroll
        for (int r = 1; r < 16; ++r) tm = fmaxf(tm, st0[r]);
#pragma unroll
        for (int r = 0; r < 16; ++r) tm = fmaxf(tm, st1[r]);
        tm = fmaxf(tm, __shfl_xor(tm, 32, 64));
        if (!__all(tm - m <= 8.0f)) {
            float nm = fmaxf(m, tm);
            float al = __expf(m - nm);
            l *= al;
            o0 *= al;
            o1 *= al;
            m = nm;
        }
        float sum = 0.0f;
#pragma unroll
        for (int r = 0; r < 16; ++r) { st0[r] = __expf(st0[r] - m); sum += st0[r]; }
#pragma unroll
        for (int r = 0; r < 16; ++r) { st1[r] = __expf(st1[r] - m); sum += st1[r]; }
        l += sum;

        bf16x8 pf[4];
#pragma unroll
        for (int c = 0; c < 4; ++c) {
            const f32x16 s_ = (c < 2) ? st0 : st1;
            const int b0 = (c & 1) * 8;
            unsigned a0 = pk2(s_[b0 + 0], s_[b0 + 1]);
            unsigned c0 = pk2(s_[b0 + 4], s_[b0 + 5]);
            unsigned a1 = pk2(s_[b0 + 2], s_[b0 + 3]);
            unsigned c1 = pk2(s_[b0 + 6], s_[b0 + 7]);
            uint2v s1 = __builtin_amdgcn_permlane32_swap(a0, c0, false, false);
            uint2v s2 = __builtin_amdgcn_permlane32_swap(a1, c1, false, false);
            pf[c] = frag4(s1[0], s2[0], s1[1], s2[1]);
        }

        __builtin_amdgcn_s_setprio(1);
#pragma unroll
        for (int c = 0; c < 4; ++c) {
            bf16x8 vf = *(const bf16x8*)(vb_ + SWZ(q, c * 32 + hi * 16));
            o0 = MFMA32(vf, pf[c], o0);
        }
#pragma unroll
        for (int c = 0; c < 4; ++c) {
            bf16x8 vf = *(const bf16x8*)(vb_ + SWZ(32 + q, c * 32 + hi * 16));
            o1 = MFMA32(vf, pf[c], o1);
        }
        __builtin_amdgcn_s_setprio(0);
    }

    float lt = l + __shfl_xor(l, 32, 64);
    float rl = 1.0f / lt;
    __syncthreads();
    const int orow = w * 32 + q;
#pragma unroll
    for (int dh = 0; dh < 2; ++dh) {
#pragma unroll
        for (int r = 0; r < 16; r += 2) {
            float v0 = (dh ? o1[r] : o0[r]) * rl;
            float v1 = (dh ? o1[r + 1] : o0[r + 1]) * rl;
            int d = dh * 32 + (r & 3) + 8 * (r >> 2) + 4 * hi;
            *(unsigned*)(smem + SWZ(orow, d * 2)) = pk2(v0, v1);
        }
    }
    __syncthreads();
    {
        const int row = tid >> 1, hf = tid & 1;
        bf16* outp = ctxh + ((size_t)bh * SS + qt * 256 + row) * 64 + hf * 32;
#pragma unroll
        for (int c = 0; c < 4; ++c) {
            bf16x8 v = *(const bf16x8*)(smem + SWZ(row, hf * 64 + c * 16));
            *(bf16x8*)(outp + c * 8) = v;
        }
    }
}

// ---------------------------------------------------------------------------
// LayerNorm: one row (1024) per block of 256 threads.
// ---------------------------------------------------------------------------
__global__ __launch_bounds__(256) void ln_kernel(const float* __restrict__ tmp,
                                                 const float* __restrict__ gamma,
                                                 const float* __restrict__ beta,
                                                 float* __restrict__ out) {
    const int row = blockIdx.x;
    const int t = threadIdx.x;
    float4 v = ((const float4*)(tmp + (size_t)row * DD))[t];
    float s = v.x + v.y + v.z + v.w;
    float ss = v.x * v.x + v.y * v.y + v.z * v.z + v.w * v.w;
#pragma unroll
    for (int mask = 1; mask <= 32; mask <<= 1) {
        s += __shfl_xor(s, mask, 64);
        ss += __shfl_xor(ss, mask, 64);
    }
    __shared__ float red[8];
    const int w = t >> 6, lane = t & 63;
    if (lane == 0) { red[w] = s; red[4 + w] = ss; }
    __syncthreads();
    s = red[0] + red[1] + red[2] + red[3];
    ss = red[4] + red[5] + red[6] + red[7];
    const float mu = s * (1.0f / 1024.0f);
    const float var = ss * (1.0f / 1024.0f) - mu * mu;
    const float rs = rsqrtf(var + 1e-6f);
    float4 gm = ((const float4*)gamma)[t];
    float4 bt = ((const float4*)beta)[t];
    float4 ov;
    ov.x = (v.x - mu) * rs * gm.x + bt.x;
    ov.y = (v.y - mu) * rs * gm.y + bt.y;
    ov.z = (v.z - mu) * rs * gm.z + bt.z;
    ov.w = (v.w - mu) * rs * gm.w + bt.w;
    ((float4*)(out + (size_t)row * DD))[t] = ov;
}

// ---------------------------------------------------------------------------
// Launcher
// ---------------------------------------------------------------------------
extern "C" void kernel_launch(void* const* d_in, const int* in_sizes, int n_in,
                              void* d_out, int out_size, void* d_ws, size_t ws_size,
                              hipStream_t stream) {
    (void)in_sizes; (void)n_in; (void)out_size; (void)ws_size;

    char* ws = (char*)d_ws;
    bf16* xb = (bf16*)ws;
    bf16* wT = (bf16*)(ws + 100663296ull);
    bf16* Qg = (bf16*)(ws + 115343360ull);
    bf16* Kg = (bf16*)(ws + 132120576ull);
    bf16* Vg = (bf16*)(ws + 148897792ull);
    bf16* ctxh = (bf16*)ws;
    bf16* Vtg = (bf16*)(ws + 16777216ull);
    float* tmp = (float*)(ws + 33554432ull);

    {
        Ptrs6 p;
        for (int j = 0; j < 6; ++j) p.p[j] = (const float*)d_in[j];
        cvt_in_kernel<<<dim3(8192, 6), 256, 0, stream>>>(p, xb);
    }
    {
        Ptrs7 p;
        for (int j = 0; j < 7; ++j) p.p[j] = (const float*)d_in[6 + j];
        cvt_w_kernel<<<dim3(32, 32, 7), dim3(32, 8), 0, stream>>>(p, wT);
    }
    {
        GemmPtrs gp;
        gp.a1[0] = xb;           gp.a1[1] = xb + NB;     gp.a1[2] = xb + 2 * NB;
        gp.a2[0] = xb + 3 * NB;  gp.a2[1] = xb + 4 * NB; gp.a2[2] = xb + 5 * NB;
        gp.b1[0] = wT;           gp.b1[1] = wT + NW;     gp.b1[2] = wT + 2 * NW;
        gp.b2[0] = wT + 3 * NW;  gp.b2[1] = wT + 4 * NW; gp.b2[2] = wT + 5 * NW;
        gp.outbh[0] = Qg; gp.outbh[1] = Kg; gp.outbh[2] = Vg;
        gemm_dp_kernel<0, 24><<<dim3(768), 512, 0, stream>>>(gp, 32, 16, nullptr, nullptr, nullptr);
    }
    vt_kernel<<<dim3(32, 64), 256, 0, stream>>>(Vg, Vtg);
    attn_kernel<<<dim3(512), 512, 0, stream>>>(Qg, Kg, Vtg, ctxh);
    {
        GemmPtrs gp;
        for (int j = 0; j < 3; ++j) {
            gp.a1[j] = ctxh; gp.a2[j] = ctxh;
            gp.b1[j] = wT + 6 * NW; gp.b2[j] = wT + 6 * NW;
            gp.outbh[j] = nullptr;
        }
        gemm_dp_kernel<1, 8><<<dim3(256), 512, 0, stream>>>(gp, 16, 16, tmp,
                                                            (const float*)d_in[0],
                                                            (const float*)d_in[3]);
    }
    ln_kernel<<<dim3(8192), 256, 0, stream>>>(tmp, (const float*)d_in[13],
                                              (const float*)d_in[14], (float*)d_out);
}